// Round 4
// baseline (945.357 us; speedup 1.0000x reference)
//
#include <hip/hip_runtime.h>

#define NN   1000
#define EE   16000
#define FF   64
#define SS   192
#define TNF  768000
#define NB   16
#define NC   10
#define LWG  256   // k_lin_chunk / partials width

typedef unsigned short u16;
typedef unsigned int   u32;
typedef float f32x4_t __attribute__((ext_vector_type(4)));
typedef short s16x4_t __attribute__((ext_vector_type(4)));
typedef short s16x8_t __attribute__((ext_vector_type(8)));

__device__ __forceinline__ float bf2f(u16 u) {
    return __uint_as_float(((u32)u) << 16);
}
__device__ __forceinline__ u16 f2bf(float f) {
    u32 u = __float_as_uint(f);
    u32 r = u + 0x7FFFu + ((u >> 16) & 1u);
    return (u16)(r >> 16);
}
// flag-dispatched scalar float load (f32m: 1 = fp32 array, 0 = bf16 array)
__device__ __forceinline__ float ldf(const void* p, size_t i, int f32m) {
    return f32m ? ((const float*)p)[i] : bf2f(((const u16*)p)[i]);
}

// pack float4 -> 4 bf16 in a uint2 (bit-identical to ushort4{f2bf(x..w)})
__device__ __forceinline__ uint2 pk4(float4 v) {
    uint2 p;
    p.x = (u32)f2bf(v.x) | ((u32)f2bf(v.y) << 16);
    p.y = (u32)f2bf(v.z) | ((u32)f2bf(v.w) << 16);
    return p;
}
// unpack low/high bf16 of a u32 word to f32
__device__ __forceinline__ float bl(u32 q) { return __uint_as_float(q << 16); }
__device__ __forceinline__ float bh(u32 q) { return __uint_as_float(q & 0xFFFF0000u); }

// ---------------- dtype detection ----------------
__global__ void k_detect(const u16* __restrict__ x, const int* __restrict__ ei,
                         int* __restrict__ flags) {
    if (threadIdx.x == 0) {
        int good = 0;
        for (int i = 0; i < 256; i += 2) {
            u16 u = x[i];
            int e = (u >> 7) & 0xFF;
            if (u == 0 || (e >= 100 && e <= 140)) ++good;
        }
        flags[0] = (good < 96) ? 1 : 0;          // <75% plausible -> fp32
        int nz = 0;
        for (int i = 1; i < 64; i += 2) nz += (ei[i] != 0);
        flags[1] = (nz <= 4) ? 1 : 0;            // odd words all zero -> int64
    }
}

// ---------------- prep kernels ----------------

__global__ void k_zero(int* __restrict__ p) {
    int i = blockIdx.x * 256 + threadIdx.x;
    if (i < 4000) p[i] = 0;
}

__global__ void k_zpart(float* __restrict__ p) {
    int i = blockIdx.x * 256 + threadIdx.x;
    if (i < LWG * 160) p[i] = 0.f;
}

__global__ void k_deg(const int* __restrict__ ei, int* __restrict__ deg,
                      const int* __restrict__ flags) {
    int e = blockIdx.x * 256 + threadIdx.x;
    const int sh = flags[1];
    if (e < EE) {
        int r = ei[(size_t)e << sh];
        int c = ei[(size_t)(EE + e) << sh];
        atomicAdd(&deg[r & 1023], 1);
        atomicAdd(&deg[NN + (c & 1023)], 1);
    }
}

__global__ __launch_bounds__(1024) void k_scan(const int* __restrict__ deg_in,
        const int* __restrict__ deg_out, int* __restrict__ ooff, int* __restrict__ ioff,
        float* __restrict__ inv_o, float* __restrict__ inv_i) {
    __shared__ int sa[1024], sb2[1024];
    const int t = threadIdx.x;
    for (int pass = 0; pass < 2; ++pass) {
        const int* deg = pass ? deg_out : deg_in;
        int* dst_off = pass ? ioff : ooff;
        sa[t] = (t < NN) ? deg[t] : 0;
        __syncthreads();
        int* src = sa; int* dst = sb2;
        for (int offn = 1; offn < 1024; offn <<= 1) {
            int v = src[t];
            if (t >= offn) v += src[t - offn];
            dst[t] = v;
            __syncthreads();
            int* tmp = src; src = dst; dst = tmp;
        }
        if (t == 0) dst_off[0] = 0;
        if (t < NN) dst_off[t + 1] = src[t];
        __syncthreads();
    }
    if (t < NN) {
        inv_o[t] = 1.0f / (float)max(deg_out[t], 1);
        inv_i[t] = 1.0f / (float)max(deg_in[t], 1);
    }
}

__global__ void k_fill(const int* __restrict__ ei, const int* __restrict__ ooff,
        const int* __restrict__ ioff, const float* __restrict__ inv_o,
        int* __restrict__ cur, int2* __restrict__ eo, int* __restrict__ eid,
        const int* __restrict__ flags) {
    int e = blockIdx.x * 256 + threadIdx.x;
    const int sh = flags[1];
    if (e < EE) {
        int r = ei[(size_t)e << sh] & 1023;
        int c = ei[(size_t)(EE + e) << sh] & 1023;
        int po = ooff[c] + atomicAdd(&cur[c], 1);       // group by dst
        eo[po] = make_int2(r, __float_as_int(inv_o[r]));
        int pi = ioff[r] + atomicAdd(&cur[NN + r], 1);  // group by src
        eid[pi] = c;
    }
}

// Wt[col][kappa], kappa = j*64 + fi.  col<64 -> z (W_z), col>=64 -> h (W_h).
__global__ void k_wt(const void* __restrict__ Wz, const void* __restrict__ Wh,
                     u16* __restrict__ wt, const int* __restrict__ flags) {
    int idx = blockIdx.x * 256 + threadIdx.x;
    if (idx >= 128 * 576) return;
    const int f32m = flags[0];
    const int col = idx / 576;
    const int kk = idx - col * 576;
    const int j = kk >> 6, fi = kk & 63;
    const void* W = (col < 64) ? Wz : Wh;
    const int fo = col & 63;
    float v;
    if (j == 0) {
        v = ldf(W, (size_t)(0 * 128 + fi) * 64 + fo, f32m)
          + ldf(W, (size_t)(5 * 128 + fi) * 64 + fo, f32m);
    } else {
        const int d = (j & 1) ? 0 : 1;
        const int kq = (j + 1) >> 1;
        v = ldf(W, (size_t)((d * 5 + kq) * 128 + fi) * 64 + fo, f32m);
    }
    wt[col * 576 + kk] = f2bf(v);
}

// ---------------- phase 1: Chebyshev basis ----------------
// basis: [sb(16)][j(9)][row(rchp)][f4(4)] bf16
// LDS state: packed bf16x4 (uint2, 8B). Recurrence history in f32 registers.
// FUSED out+in gather: both directions' 4-batched chains interleaved in ONE
// loop -> 8 independent load chains in flight per iteration (was 2x4
// sequential). Ragged trips handled by clamped indices + 0/1 validity
// weights (fmaf with 0 weight is exact no-op; with 1.0 matches the old add).

__device__ __forceinline__ void gOI(const uint2* __restrict__ SO, const uint2* __restrict__ SI,
                                    const int2* __restrict__ eo, const int* __restrict__ eid,
                                    int e0o, int e1o, int e0i, int e1i,
                                    float4& ao, float4& ai) {
    ao = make_float4(0.f, 0.f, 0.f, 0.f);
    ai = make_float4(0.f, 0.f, 0.f, 0.f);
    const int lO = e1o - 1, lI = e1i - 1;   // degrees >= 1 guaranteed (ring)
    int eO = e0o, eI = e0i;
    while (eO < e1o || eI < e1i) {
        const int a0 = min(eO, lO),     a1 = min(eO + 1, lO),
                  a2 = min(eO + 2, lO), a3 = min(eO + 3, lO);
        const int b0 = min(eI, lI),     b1 = min(eI + 1, lI),
                  b2 = min(eI + 2, lI), b3 = min(eI + 3, lI);
        // 8 independent meta loads (global, L2-hot)
        int2 p0 = eo[a0], p1 = eo[a1], p2 = eo[a2], p3 = eo[a3];
        int  i0 = eid[b0], i1 = eid[b1], i2 = eid[b2], i3 = eid[b3];
        const float w0 = (eO     < e1o) ? __int_as_float(p0.y) : 0.f;
        const float w1 = (eO + 1 < e1o) ? __int_as_float(p1.y) : 0.f;
        const float w2 = (eO + 2 < e1o) ? __int_as_float(p2.y) : 0.f;
        const float w3 = (eO + 3 < e1o) ? __int_as_float(p3.y) : 0.f;
        const float u0 = (eI     < e1i) ? 1.f : 0.f;
        const float u1 = (eI + 1 < e1i) ? 1.f : 0.f;
        const float u2 = (eI + 2 < e1i) ? 1.f : 0.f;
        const float u3 = (eI + 3 < e1i) ? 1.f : 0.f;
        // 8 independent LDS gathers
        uint2 q0 = SO[p0.x], q1 = SO[p1.x], q2 = SO[p2.x], q3 = SO[p3.x];
        uint2 r0 = SI[i0],   r1 = SI[i1],   r2 = SI[i2],   r3 = SI[i3];
        ao.x = fmaf(w0, bl(q0.x), ao.x); ao.y = fmaf(w0, bh(q0.x), ao.y);
        ao.z = fmaf(w0, bl(q0.y), ao.z); ao.w = fmaf(w0, bh(q0.y), ao.w);
        ao.x = fmaf(w1, bl(q1.x), ao.x); ao.y = fmaf(w1, bh(q1.x), ao.y);
        ao.z = fmaf(w1, bl(q1.y), ao.z); ao.w = fmaf(w1, bh(q1.y), ao.w);
        ao.x = fmaf(w2, bl(q2.x), ao.x); ao.y = fmaf(w2, bh(q2.x), ao.y);
        ao.z = fmaf(w2, bl(q2.y), ao.z); ao.w = fmaf(w2, bh(q2.y), ao.w);
        ao.x = fmaf(w3, bl(q3.x), ao.x); ao.y = fmaf(w3, bh(q3.x), ao.y);
        ao.z = fmaf(w3, bl(q3.y), ao.z); ao.w = fmaf(w3, bh(q3.y), ao.w);
        ai.x = fmaf(u0, bl(r0.x), ai.x); ai.y = fmaf(u0, bh(r0.x), ai.y);
        ai.z = fmaf(u0, bl(r0.y), ai.z); ai.w = fmaf(u0, bh(r0.y), ai.w);
        ai.x = fmaf(u1, bl(r1.x), ai.x); ai.y = fmaf(u1, bh(r1.x), ai.y);
        ai.z = fmaf(u1, bl(r1.y), ai.z); ai.w = fmaf(u1, bh(r1.y), ai.w);
        ai.x = fmaf(u2, bl(r2.x), ai.x); ai.y = fmaf(u2, bh(r2.x), ai.y);
        ai.z = fmaf(u2, bl(r2.y), ai.z); ai.w = fmaf(u2, bh(r2.y), ai.w);
        ai.x = fmaf(u3, bl(r3.x), ai.x); ai.y = fmaf(u3, bh(r3.x), ai.y);
        ai.z = fmaf(u3, bl(r3.y), ai.z); ai.w = fmaf(u3, bh(r3.y), ai.w);
        eO += 4; eI += 4;
    }
}

// Phase/hazard plan (identity node mapping, coalesced stores):
//  init: bX = x (bf16), rx = x (f32 regs), j0
//  ph12: gathers read bX; writes bA=T1o (j1), bB=T1i (j2); rt1o = T1o
//  ph34: gathers read bA,bB; writes bC=T2o (j3), bX=T2i (j4); sub rx; rt2o = T2o
//  ph56: gathers read bC,bX; writes bB=T3o (j5), bA=T3i (j6); sub rt1o (both dirs)
//  ph78: gathers read bB,bA; no LDS writes (j7,j8); sub rt2o (both dirs)
__global__ __launch_bounds__(1024) void k_cheb(const void* __restrict__ xv_,
        const int2* __restrict__ eo, const int* __restrict__ ooff,
        const int* __restrict__ eid, const int* __restrict__ ioff,
        const float* __restrict__ inv_i, u16* __restrict__ basis, int s0, int rchp,
        const int* __restrict__ flags, int chs) {
    __shared__ uint2 bX[NN], bA[NN], bB[NN], bC[NN];
    // swizzle: sb = blockIdx/chs so all 16 slices of a snapshot share an XCD (chs % 8 == 0)
    const int sb = blockIdx.x / chs;
    const int slocal = blockIdx.x - sb * chs;
    const int s = s0 + slocal;
    const int n = threadIdx.x;
    const bool act = (n < NN);
    const int f32m = flags[0];
    int e0o = 0, e1o = 0, e0i = 0, e1i = 0;
    float fiv = 0.f;
    const int row = slocal * NN + n;
    if (act) {
        e0o = ooff[n]; e1o = ooff[n + 1];
        e0i = ioff[n]; e1i = ioff[n + 1];
        fiv = inv_i[n];
    }
    const float fiv2 = 2.f * fiv;
    u16* const bp = basis + (size_t)(sb * 9) * rchp * 4 + (size_t)row * 4;
    const size_t jstep = (size_t)rchp * 4;   // u16s per j-plane
    float4 rx, rt1o, rt2o;
    if (act) {
        const size_t xoff = ((size_t)s * NN + n) * FF + sb * 4;
        if (f32m) {
            rx = *(const float4*)((const float*)xv_ + xoff);
        } else {
            ushort4 u = *(const ushort4*)((const u16*)xv_ + xoff);
            rx = make_float4(bf2f(u.x), bf2f(u.y), bf2f(u.z), bf2f(u.w));
        }
        uint2 p = pk4(rx);
        bX[n] = p;
        *(uint2*)bp = p;                              // j0
    }
    __syncthreads();
    // ph12
    if (act) {
        float4 go, gi;
        gOI(bX, bX, eo, eid, e0o, e1o, e0i, e1i, go, gi);
        rt1o = go;
        uint2 pa = pk4(go);
        bA[n] = pa; *(uint2*)(bp + jstep) = pa;       // j1
        float4 t = make_float4(gi.x * fiv, gi.y * fiv, gi.z * fiv, gi.w * fiv);
        uint2 pb = pk4(t);
        bB[n] = pb; *(uint2*)(bp + 2 * jstep) = pb;   // j2
    }
    __syncthreads();
    // ph34: T2o = 2*gO(bA)-x ; T2i = fiv2*gI(bB)-x
    if (act) {
        float4 go, gi;
        gOI(bA, bB, eo, eid, e0o, e1o, e0i, e1i, go, gi);
        float4 t2o = make_float4(fmaf(2.f, go.x, -rx.x), fmaf(2.f, go.y, -rx.y),
                                 fmaf(2.f, go.z, -rx.z), fmaf(2.f, go.w, -rx.w));
        rt2o = t2o;
        uint2 pc = pk4(t2o);
        bC[n] = pc; *(uint2*)(bp + 3 * jstep) = pc;   // j3
        float4 t2i = make_float4(fmaf(fiv2, gi.x, -rx.x), fmaf(fiv2, gi.y, -rx.y),
                                 fmaf(fiv2, gi.z, -rx.z), fmaf(fiv2, gi.w, -rx.w));
        uint2 px = pk4(t2i);
        bX[n] = px; *(uint2*)(bp + 4 * jstep) = px;   // j4
    }
    __syncthreads();
    // ph56: T3o = 2*gO(bC)-T1o ; T3i = fiv2*gI(bX)-T1o   (quirk: both subtract T1o)
    if (act) {
        float4 go, gi;
        gOI(bC, bX, eo, eid, e0o, e1o, e0i, e1i, go, gi);
        float4 t3o = make_float4(fmaf(2.f, go.x, -rt1o.x), fmaf(2.f, go.y, -rt1o.y),
                                 fmaf(2.f, go.z, -rt1o.z), fmaf(2.f, go.w, -rt1o.w));
        uint2 pb = pk4(t3o);
        bB[n] = pb; *(uint2*)(bp + 5 * jstep) = pb;   // j5
        float4 t3i = make_float4(fmaf(fiv2, gi.x, -rt1o.x), fmaf(fiv2, gi.y, -rt1o.y),
                                 fmaf(fiv2, gi.z, -rt1o.z), fmaf(fiv2, gi.w, -rt1o.w));
        uint2 pa = pk4(t3i);
        bA[n] = pa; *(uint2*)(bp + 6 * jstep) = pa;   // j6
    }
    __syncthreads();
    // ph78: T4o = 2*gO(bB)-T2o ; T4i = fiv2*gI(bA)-T2o   (quirk: both subtract T2o)
    if (act) {
        float4 go, gi;
        gOI(bB, bA, eo, eid, e0o, e1o, e0i, e1i, go, gi);
        float4 t4o = make_float4(fmaf(2.f, go.x, -rt2o.x), fmaf(2.f, go.y, -rt2o.y),
                                 fmaf(2.f, go.z, -rt2o.z), fmaf(2.f, go.w, -rt2o.w));
        *(uint2*)(bp + 7 * jstep) = pk4(t4o);         // j7
        float4 t4i = make_float4(fmaf(fiv2, gi.x, -rt2o.x), fmaf(fiv2, gi.y, -rt2o.y),
                                 fmaf(fiv2, gi.z, -rt2o.z), fmaf(fiv2, gi.w, -rt2o.w));
        *(uint2*)(bp + 8 * jstep) = pk4(t4i);         // j8
    }
}

// ---------------- phase 2: GEMM [rchp,576]@[576,128] + gates + LN -> hnc (chunk-local) ----------------

__global__ __launch_bounds__(256, 4) void k_gemm(const u16* __restrict__ basis,
        const u16* __restrict__ wt, const void* __restrict__ bz, const void* __restrict__ bh,
        const void* __restrict__ lng, const void* __restrict__ lnb, u16* __restrict__ hnc,
        int rchp, int rchv, const int* __restrict__ flags) {
    union SM {
        struct { u16 A[8 * 128 * 4]; u16 B[128 * 40]; } st;
        float heh[128 * 65];
    };
    __shared__ SM sm;
    __shared__ float sMu[128], sRs[128];
    __shared__ float sBz[64], sBh[64], sG[64], sB2[64];

    const int tid = threadIdx.x;
    if (tid < 64) {
        const int f32m = flags[0];
        sBz[tid] = ldf(bz, tid, f32m); sBh[tid] = ldf(bh, tid, f32m);
        sG[tid] = ldf(lng, tid, f32m); sB2[tid] = ldf(lnb, tid, f32m);
    }
    const int lane = tid & 63, wv = tid >> 6;
    const int wr = wv >> 1, wc = wv & 1;
    const int m = lane & 15, q = lane >> 4;
    const int r0 = blockIdx.x * 128;

    f32x4_t acc[4][4];
    const f32x4_t zero = {0.f, 0.f, 0.f, 0.f};
    for (int mi = 0; mi < 4; ++mi)
        for (int ni = 0; ni < 4; ++ni) acc[mi][ni] = zero;

    for (int t = 0; t < 18; ++t) {
        const int j = t >> 1, hf = t & 1;
        #pragma unroll
        for (int p = 0; p < 2; ++p) {
            int lin = p * 256 + tid;
            int sbp = lin >> 6, rp = lin & 63;
            const u16* src = basis + ((size_t)((hf * 8 + sbp) * 9 + j) * rchp + r0 + rp * 2) * 4;
            *(uint4*)(&sm.st.A[lin * 8]) = *(const uint4*)src;
        }
        #pragma unroll
        for (int p = 0; p < 2; ++p) {
            int lin = p * 256 + tid;
            int c = lin >> 2, qq = lin & 3;
            const u16* src = wt + c * 576 + t * 32 + qq * 8;
            *(uint4*)(&sm.st.B[c * 40 + qq * 8]) = *(const uint4*)src;
        }
        __syncthreads();
        s16x8_t af[4], bfr[4];
        #pragma unroll
        for (int mi = 0; mi < 4; ++mi) {
            int r = wr * 64 + mi * 16 + m;
            s16x4_t lo = *(const s16x4_t*)&sm.st.A[(2 * q) * 512 + r * 4];
            s16x4_t hi = *(const s16x4_t*)&sm.st.A[(2 * q + 1) * 512 + r * 4];
            af[mi] = __builtin_shufflevector(lo, hi, 0, 1, 2, 3, 4, 5, 6, 7);
        }
        #pragma unroll
        for (int ni = 0; ni < 4; ++ni) {
            int c = (ni < 2) ? (wc * 32 + ni * 16 + m) : (64 + wc * 32 + (ni - 2) * 16 + m);
            bfr[ni] = *(const s16x8_t*)&sm.st.B[c * 40 + q * 8];
        }
        #pragma unroll
        for (int mi = 0; mi < 4; ++mi)
            #pragma unroll
            for (int ni = 0; ni < 4; ++ni)
                acc[mi][ni] = __builtin_amdgcn_mfma_f32_16x16x32_bf16(af[mi], bfr[ni], acc[mi][ni], 0, 0, 0);
        __syncthreads();
    }

    #pragma unroll
    for (int mi = 0; mi < 4; ++mi) {
        #pragma unroll
        for (int ni = 0; ni < 2; ++ni) {
            const int f = wc * 32 + ni * 16 + m;
            const float vbz = sBz[f], vbh = sBh[f];
            #pragma unroll
            for (int r = 0; r < 4; ++r) {
                const int rl = wr * 64 + mi * 16 + q * 4 + r;
                float zp = acc[mi][ni][r];
                float hp = acc[mi][ni + 2][r];
                zp = (zp == zp) ? zp : 0.f;
                hp = (hp == hp) ? hp : 0.f;
                zp = fminf(fmaxf(zp + vbz, -30.f), 30.f);
                hp = fminf(fmaxf(hp + vbh, -15.f), 15.f);
                const float z = __fdividef(1.f, 1.f + __expf(-zp));
                const float e2 = __expf(2.f * hp);
                const float ht = __fdividef(e2 - 1.f, e2 + 1.f);
                float h = (1.f - z) * ht;
                h = fmaxf(h, 0.f);
                sm.heh[rl * 65 + f] = h;
            }
        }
    }
    __syncthreads();
    if (tid < 128) {
        float sum = 0.f, ss = 0.f;
        #pragma unroll 8
        for (int f = 0; f < 64; ++f) {
            float v = sm.heh[tid * 65 + f];
            sum += v; ss += v * v;
        }
        float mu = sum * 0.015625f;
        float var = fmaxf(ss * 0.015625f - mu * mu, 0.f);
        sMu[tid] = mu;
        sRs[tid] = rsqrtf(var + 1e-5f);
    }
    __syncthreads();
    for (int idx = tid; idx < 128 * 64; idx += 256) {
        int rl = idx >> 6, f = idx & 63;
        if (r0 + rl < rchv) {
            float v = (sm.heh[rl * 65 + f] - sMu[rl]) * sRs[rl] * sG[f] + sB2[f];
            hnc[(size_t)(r0 + rl) * 64 + f] = f2bf(v);
        }
    }
}

// ---------------- phase 3: chunked final linear (accumulates into partials) ----------------

__global__ __launch_bounds__(256) void k_lin_chunk(const u16* __restrict__ hnc,
        const void* __restrict__ lw, float* __restrict__ partials, int s0, int chs,
        const int* __restrict__ flags) {
    const int tid = threadIdx.x;
    const int f32m = flags[0];
    float acc[NB][NC];
    #pragma unroll
    for (int b = 0; b < NB; ++b)
        #pragma unroll
        for (int c = 0; c < NC; ++c) acc[b][c] = 0.f;

    const int hi_s = s0 + chs - 1;
    for (int w = blockIdx.x * 256 + tid; w < TNF; w += LWG * 256) {
        const int t = w / 64000;
        int blo_n = s0 - t + 11;
        const int blo = (blo_n > 0) ? (blo_n / 12) : 0;
        const int bhi_n = hi_s - t;
        const int bhi = (bhi_n >= 0) ? (bhi_n / 12) : -1;
        if (bhi < blo) continue;
        float wvv[NC];
        if (f32m) {
            #pragma unroll
            for (int c = 0; c < NC; ++c) wvv[c] = ((const float*)lw)[(size_t)c * TNF + w];
        } else {
            #pragma unroll
            for (int c = 0; c < NC; ++c) wvv[c] = bf2f(((const u16*)lw)[(size_t)c * TNF + w]);
        }
        #pragma unroll
        for (int c = 0; c < NC; ++c) {
            float v = wvv[c];
            wvv[c] = (v == v && v > -1e30f && v < 1e30f) ? v : 0.f;
        }
        #pragma unroll
        for (int b = 0; b < NB; ++b) {
            if (b >= blo && b <= bhi) {
                const int sl = b * 12 + t - s0;
                const float h = bf2f(hnc[(size_t)sl * 64000 + (w - t * 64000)]);
                #pragma unroll
                for (int c = 0; c < NC; ++c) acc[b][c] = fmaf(h, wvv[c], acc[b][c]);
            }
        }
    }
    __shared__ float sRed[4][160];
    const int wvi = tid >> 6, lane = tid & 63;
    #pragma unroll
    for (int b = 0; b < NB; ++b)
        #pragma unroll
        for (int c = 0; c < NC; ++c) {
            float v = acc[b][c];
            #pragma unroll
            for (int off = 1; off < 64; off <<= 1) v += __shfl_xor(v, off, 64);
            if (lane == 0) sRed[wvi][b * NC + c] = v;
        }
    __syncthreads();
    if (tid < 160)
        partials[(size_t)blockIdx.x * 160 + tid] +=
            sRed[0][tid] + sRed[1][tid] + sRed[2][tid] + sRed[3][tid];
}

__global__ void k_red(const float* __restrict__ partials, const void* __restrict__ lb,
                      void* __restrict__ out, const int* __restrict__ flags) {
    const int o = threadIdx.x;
    const int f32m = flags[0];
    if (o < 160) {
        float s = ldf(lb, o % NC, f32m);
        #pragma unroll 8
        for (int wg = 0; wg < LWG; ++wg) s += partials[(size_t)wg * 160 + o];
        if (f32m) ((float*)out)[o] = s;
        else      ((u16*)out)[o] = f2bf(s);
    }
}

// ---------------- launch ----------------

extern "C" void kernel_launch(void* const* d_in, const int* in_sizes, int n_in,
                              void* d_out, int out_size, void* d_ws, size_t ws_size,
                              hipStream_t stream) {
    (void)in_sizes; (void)n_in; (void)out_size;
    const void* x   = d_in[0];
    const int*  ei  = (const int*)d_in[1];
    const void* Wz  = d_in[2];
    const void* bz  = d_in[3];
    const void* Wh  = d_in[6];
    const void* bh  = d_in[7];
    const void* lng = d_in[8];
    const void* lnb = d_in[9];
    const void* lw  = d_in[10];
    const void* lb  = d_in[11];

    char* ws = (char*)d_ws;
    size_t off = 0;
    auto alloc = [&](size_t bytes) -> void* {
        void* p = ws + off;
        off = (off + bytes + 255) & ~(size_t)255;
        return p;
    };
    int*   flags    = (int*)  alloc(64);
    u16*   wt       = (u16*)  alloc(128 * 576 * 2);
    int*   ints     = (int*)  alloc(4000 * 4);
    int*   ooff     = (int*)  alloc(1024 * 4);
    int*   ioff     = (int*)  alloc(1024 * 4);
    float* inv_o    = (float*)alloc(1000 * 4);
    float* inv_i    = (float*)alloc(1000 * 4);
    int2*  eo       = (int2*) alloc((size_t)EE * 8);
    int*   eid      = (int*)  alloc((size_t)EE * 4);
    float* partials = (float*)alloc((size_t)LWG * 160 * 4);

    const int cand[] = {192, 96, 64, 48, 32, 24, 16, 12, 8, 6, 4, 3, 2, 1};
    int CHS = 1, RCHP = 1024;
    for (int ci = 0; ci < 14; ++ci) {
        int c = cand[ci];
        int rchp = ((c * NN + 127) / 128) * 128;
        size_t need = (size_t)16 * 9 * rchp * 8 + (size_t)c * NN * FF * 2 + 8192;
        if (off + need <= ws_size) { CHS = c; RCHP = rchp; break; }
    }
    u16* basis = (u16*)alloc((size_t)16 * 9 * RCHP * 8);
    u16* hnc   = (u16*)alloc((size_t)CHS * NN * FF * 2);

    int* deg_out = ints;
    int* deg_in  = ints + 1000;
    int* cur     = ints + 2000;

    k_detect<<<1, 64, 0, stream>>>((const u16*)x, ei, flags);
    k_zero<<<16, 256, 0, stream>>>(ints);
    k_zpart<<<(LWG * 160 + 255) / 256, 256, 0, stream>>>(partials);
    k_deg<<<(EE + 255) / 256, 256, 0, stream>>>(ei, ints, flags);
    k_scan<<<1, 1024, 0, stream>>>(deg_in, deg_out, ooff, ioff, inv_o, inv_i);
    k_fill<<<(EE + 255) / 256, 256, 0, stream>>>(ei, ooff, ioff, inv_o, cur, eo, eid, flags);
    k_wt<<<288, 256, 0, stream>>>(Wz, Wh, wt, flags);
    const int nchunk = SS / CHS;
    for (int ch = 0; ch < nchunk; ++ch) {
        k_cheb<<<CHS * 16, 1024, 0, stream>>>(x, eo, ooff, eid, ioff, inv_i, basis,
                                              ch * CHS, RCHP, flags, CHS);
        k_gemm<<<RCHP / 128, 256, 0, stream>>>(basis, wt, bz, bh, lng, lnb, hnc,
                                               RCHP, CHS * NN, flags);
        k_lin_chunk<<<LWG, 256, 0, stream>>>(hnc, lw, partials, ch * CHS, CHS, flags);
    }
    k_red<<<1, 256, 0, stream>>>(partials, lb, d_out, flags);
}

// Round 5
// 548.687 us; speedup vs baseline: 1.7229x; 1.7229x over previous
//
#include <hip/hip_runtime.h>

#define NN   1000
#define EE   16000
#define FF   64
#define SS   192
#define TNF  768000
#define NB   16
#define NC   10
#define LWG  256   // k_lin_chunk / partials width
#define EPAD 24576 // padded edge-list capacity (sum ceil(deg/8)*8 <= 23000)

typedef unsigned short u16;
typedef unsigned int   u32;
typedef float f32x4_t __attribute__((ext_vector_type(4)));
typedef short s16x4_t __attribute__((ext_vector_type(4)));
typedef short s16x8_t __attribute__((ext_vector_type(8)));

__device__ __forceinline__ float bf2f(u16 u) {
    return __uint_as_float(((u32)u) << 16);
}
__device__ __forceinline__ u16 f2bf(float f) {
    u32 u = __float_as_uint(f);
    u32 r = u + 0x7FFFu + ((u >> 16) & 1u);
    return (u16)(r >> 16);
}
// flag-dispatched scalar float load (f32m: 1 = fp32 array, 0 = bf16 array)
__device__ __forceinline__ float ldf(const void* p, size_t i, int f32m) {
    return f32m ? ((const float*)p)[i] : bf2f(((const u16*)p)[i]);
}

// pack float4 -> 4 bf16 in a uint2 (bit-identical to ushort4{f2bf(x..w)})
__device__ __forceinline__ uint2 pk4(float4 v) {
    uint2 p;
    p.x = (u32)f2bf(v.x) | ((u32)f2bf(v.y) << 16);
    p.y = (u32)f2bf(v.z) | ((u32)f2bf(v.w) << 16);
    return p;
}
// unpack low/high bf16 of a u32 word to f32
__device__ __forceinline__ float bl(u32 q) { return __uint_as_float(q << 16); }
__device__ __forceinline__ float bh(u32 q) { return __uint_as_float(q & 0xFFFF0000u); }

// ---------------- dtype detection ----------------
__global__ void k_detect(const u16* __restrict__ x, const int* __restrict__ ei,
                         int* __restrict__ flags) {
    if (threadIdx.x == 0) {
        int good = 0;
        for (int i = 0; i < 256; i += 2) {
            u16 u = x[i];
            int e = (u >> 7) & 0xFF;
            if (u == 0 || (e >= 100 && e <= 140)) ++good;
        }
        flags[0] = (good < 96) ? 1 : 0;          // <75% plausible -> fp32
        int nz = 0;
        for (int i = 1; i < 64; i += 2) nz += (ei[i] != 0);
        flags[1] = (nz <= 4) ? 1 : 0;            // odd words all zero -> int64
    }
}

// ---------------- prep kernels ----------------

__global__ void k_zero(int* __restrict__ p) {
    int i = blockIdx.x * 256 + threadIdx.x;
    if (i < 4000) p[i] = 0;
}

__global__ void k_zpart(float* __restrict__ p) {
    int i = blockIdx.x * 256 + threadIdx.x;
    if (i < LWG * 160) p[i] = 0.f;
}

// prefill padded edge lists with dummy index 1000 (reads LDS zero slot)
__global__ void k_fille(u16* __restrict__ a, u16* __restrict__ b) {
    int i = blockIdx.x * 256 + threadIdx.x;
    if (i < EPAD / 2) {
        ((u32*)a)[i] = 0x03E803E8u;
        ((u32*)b)[i] = 0x03E803E8u;
    }
}

__global__ void k_deg(const int* __restrict__ ei, int* __restrict__ deg,
                      const int* __restrict__ flags) {
    int e = blockIdx.x * 256 + threadIdx.x;
    const int sh = flags[1];
    if (e < EE) {
        int r = ei[(size_t)e << sh];
        int c = ei[(size_t)(EE + e) << sh];
        atomicAdd(&deg[r & 1023], 1);
        atomicAdd(&deg[NN + (c & 1023)], 1);
    }
}

// 8-padded CSR offsets: ooffp from ceil(deg_in/8)*8 (edges grouped by dst),
// ioffp from ceil(deg_out/8)*8 (edges grouped by src). Plus inverse degrees.
__global__ __launch_bounds__(1024) void k_scan(const int* __restrict__ deg_in,
        const int* __restrict__ deg_out, int* __restrict__ ooffp, int* __restrict__ ioffp,
        float* __restrict__ inv_o, float* __restrict__ inv_i) {
    __shared__ int sa[1024], sb2[1024];
    const int t = threadIdx.x;
    for (int pass = 0; pass < 2; ++pass) {
        const int* deg = pass ? deg_out : deg_in;
        int* dst_off = pass ? ioffp : ooffp;
        sa[t] = (t < NN) ? ((deg[t] + 7) & ~7) : 0;
        __syncthreads();
        int* src = sa; int* dst = sb2;
        for (int offn = 1; offn < 1024; offn <<= 1) {
            int v = src[t];
            if (t >= offn) v += src[t - offn];
            dst[t] = v;
            __syncthreads();
            int* tmp = src; src = dst; dst = tmp;
        }
        if (t == 0) dst_off[0] = 0;
        if (t < NN) dst_off[t + 1] = src[t];
        __syncthreads();
    }
    if (t < NN) {
        inv_o[t] = 1.0f / (float)max(deg_out[t], 1);
        inv_i[t] = 1.0f / (float)max(deg_in[t], 1);
    }
}

__global__ void k_fill(const int* __restrict__ ei, const int* __restrict__ ooffp,
        const int* __restrict__ ioffp, int* __restrict__ cur,
        u16* __restrict__ eo_s, u16* __restrict__ eid_s,
        const int* __restrict__ flags) {
    int e = blockIdx.x * 256 + threadIdx.x;
    const int sh = flags[1];
    if (e < EE) {
        int r = ei[(size_t)e << sh] & 1023;
        int c = ei[(size_t)(EE + e) << sh] & 1023;
        int po = ooffp[c] + atomicAdd(&cur[c], 1);       // group by dst
        eo_s[po] = (u16)r;
        int pi = ioffp[r] + atomicAdd(&cur[NN + r], 1);  // group by src
        eid_s[pi] = (u16)c;
    }
}

// Wt[col][kappa], kappa = j*64 + fi.  col<64 -> z (W_z), col>=64 -> h (W_h).
__global__ void k_wt(const void* __restrict__ Wz, const void* __restrict__ Wh,
                     u16* __restrict__ wt, const int* __restrict__ flags) {
    int idx = blockIdx.x * 256 + threadIdx.x;
    if (idx >= 128 * 576) return;
    const int f32m = flags[0];
    const int col = idx / 576;
    const int kk = idx - col * 576;
    const int j = kk >> 6, fi = kk & 63;
    const void* W = (col < 64) ? Wz : Wh;
    const int fo = col & 63;
    float v;
    if (j == 0) {
        v = ldf(W, (size_t)(0 * 128 + fi) * 64 + fo, f32m)
          + ldf(W, (size_t)(5 * 128 + fi) * 64 + fo, f32m);
    } else {
        const int d = (j & 1) ? 0 : 1;
        const int kq = (j + 1) >> 1;
        v = ldf(W, (size_t)((d * 5 + kq) * 128 + fi) * 64 + fo, f32m);
    }
    wt[col * 576 + kk] = f2bf(v);
}

// ---------------- phase 1: Chebyshev basis ----------------
// basis: [sb(16)][j(9)][row(rchp)][f4(4)] bf16
// Out-chain LDS buffers hold PREMULTIPLIED values (inv_o[n] * T_ko[n]) so the
// out-gather is a pure sum -> edge metadata is a bare u16 src index.
// In-chain buffers hold raw values (weight inv_i applied after the sum).
// Edge lists: u16 node ids, per-node 8-padded (dummy=1000 -> zeroed LDS slot),
// so each lane loads 8 edges with ONE aligned dwordx4 -> 8x fewer scattered
// VMEM lane-addresses (the R2/R4-identified binder).
// Raw recurrence history (x, T1o, T2o) in f32 registers (quirk-exact).

__device__ __forceinline__ float4 g8(const uint2* __restrict__ S,
                                     const u16* __restrict__ lst, int e0, int e1) {
    float4 a = make_float4(0.f, 0.f, 0.f, 0.f);
    for (int e = e0; e < e1; e += 8) {
        uint4 w = *(const uint4*)(lst + e);   // 8 u16 indices, 16B aligned
        int i0 = w.x & 0xFFFF, i1 = w.x >> 16;
        int i2 = w.y & 0xFFFF, i3 = w.y >> 16;
        int i4 = w.z & 0xFFFF, i5 = w.z >> 16;
        int i6 = w.w & 0xFFFF, i7 = w.w >> 16;
        uint2 q0 = S[i0], q1 = S[i1], q2 = S[i2], q3 = S[i3];
        uint2 q4 = S[i4], q5 = S[i5], q6 = S[i6], q7 = S[i7];
        a.x += bl(q0.x) + bl(q1.x) + bl(q2.x) + bl(q3.x)
             + bl(q4.x) + bl(q5.x) + bl(q6.x) + bl(q7.x);
        a.y += bh(q0.x) + bh(q1.x) + bh(q2.x) + bh(q3.x)
             + bh(q4.x) + bh(q5.x) + bh(q6.x) + bh(q7.x);
        a.z += bl(q0.y) + bl(q1.y) + bl(q2.y) + bl(q3.y)
             + bl(q4.y) + bl(q5.y) + bl(q6.y) + bl(q7.y);
        a.w += bh(q0.y) + bh(q1.y) + bh(q2.y) + bh(q3.y)
             + bh(q4.y) + bh(q5.y) + bh(q6.y) + bh(q7.y);
    }
    return a;
}

// Phase/buffer plan (4 x 1024-entry buffers; entries 1000..1023 stay zero):
//  init: bXo = premult x, bXi = raw x; j0 = raw x
//  ph12: read bXo,bXi -> write bA = premult T1o (j1 raw), bB = raw T1i (j2)
//  ph34: read bA,bB   -> write bXo = premult T2o (j3 raw), bXi = raw T2i (j4); sub rx
//  ph56: read bXo,bXi -> write bA = premult T3o (j5 raw), bB = raw T3i (j6); sub rt1o (both)
//  ph78: read bA,bB   -> j7, j8; sub rt2o (both); no LDS writes
__global__ __launch_bounds__(1024) void k_cheb(const void* __restrict__ xv_,
        const u16* __restrict__ eo_s, const int* __restrict__ ooffp,
        const u16* __restrict__ eid_s, const int* __restrict__ ioffp,
        const float* __restrict__ inv_o, const float* __restrict__ inv_i,
        u16* __restrict__ basis, int s0, int rchp,
        const int* __restrict__ flags, int chs) {
    __shared__ uint2 bXo[1024], bXi[1024], bA[1024], bB[1024];
    // swizzle: sb = blockIdx/chs so all 16 slices of a snapshot share an XCD (chs % 8 == 0)
    const int sb = blockIdx.x / chs;
    const int slocal = blockIdx.x - sb * chs;
    const int s = s0 + slocal;
    const int n = threadIdx.x;
    const bool act = (n < NN);
    const int f32m = flags[0];
    int e0o = 0, e1o = 0, e0i = 0, e1i = 0;
    float fiv = 0.f, fov = 0.f;
    const int row = slocal * NN + n;
    if (act) {
        e0o = ooffp[n]; e1o = ooffp[n + 1];
        e0i = ioffp[n]; e1i = ioffp[n + 1];
        fiv = inv_i[n];
        fov = inv_o[n];
    }
    const float fiv2 = 2.f * fiv;
    u16* const bp = basis + (size_t)(sb * 9) * rchp * 4 + (size_t)row * 4;
    const size_t jstep = (size_t)rchp * 4;   // u16s per j-plane
    float4 rx, rt1o, rt2o;
    if (n >= NN) {   // zero the dummy slots (1000..1023) in all buffers
        const uint2 z = make_uint2(0u, 0u);
        bXo[n] = z; bXi[n] = z; bA[n] = z; bB[n] = z;
    }
    if (act) {
        const size_t xoff = ((size_t)s * NN + n) * FF + sb * 4;
        if (f32m) {
            rx = *(const float4*)((const float*)xv_ + xoff);
        } else {
            ushort4 u = *(const ushort4*)((const u16*)xv_ + xoff);
            rx = make_float4(bf2f(u.x), bf2f(u.y), bf2f(u.z), bf2f(u.w));
        }
        bXi[n] = pk4(rx);
        bXo[n] = pk4(make_float4(fov * rx.x, fov * rx.y, fov * rx.z, fov * rx.w));
        *(uint2*)bp = pk4(rx);                          // j0 raw
    }
    __syncthreads();
    // ph12: T1o = sum(bXo) ; T1i = fiv * sum(bXi)
    if (act) {
        float4 go = g8(bXo, eo_s, e0o, e1o);
        float4 gi = g8(bXi, eid_s, e0i, e1i);
        rt1o = go;
        bA[n] = pk4(make_float4(fov * go.x, fov * go.y, fov * go.z, fov * go.w));
        *(uint2*)(bp + jstep) = pk4(go);                // j1 raw
        float4 t = make_float4(gi.x * fiv, gi.y * fiv, gi.z * fiv, gi.w * fiv);
        bB[n] = pk4(t);
        *(uint2*)(bp + 2 * jstep) = pk4(t);             // j2 raw
    }
    __syncthreads();
    // ph34: T2o = 2*sum(bA) - x ; T2i = fiv2*sum(bB) - x
    if (act) {
        float4 go = g8(bA, eo_s, e0o, e1o);
        float4 gi = g8(bB, eid_s, e0i, e1i);
        float4 t2o = make_float4(fmaf(2.f, go.x, -rx.x), fmaf(2.f, go.y, -rx.y),
                                 fmaf(2.f, go.z, -rx.z), fmaf(2.f, go.w, -rx.w));
        rt2o = t2o;
        bXo[n] = pk4(make_float4(fov * t2o.x, fov * t2o.y, fov * t2o.z, fov * t2o.w));
        *(uint2*)(bp + 3 * jstep) = pk4(t2o);           // j3 raw
        float4 t2i = make_float4(fmaf(fiv2, gi.x, -rx.x), fmaf(fiv2, gi.y, -rx.y),
                                 fmaf(fiv2, gi.z, -rx.z), fmaf(fiv2, gi.w, -rx.w));
        bXi[n] = pk4(t2i);
        *(uint2*)(bp + 4 * jstep) = pk4(t2i);           // j4 raw
    }
    __syncthreads();
    // ph56: T3o = 2*sum(bXo) - T1o ; T3i = fiv2*sum(bXi) - T1o (quirk: both T1o)
    if (act) {
        float4 go = g8(bXo, eo_s, e0o, e1o);
        float4 gi = g8(bXi, eid_s, e0i, e1i);
        float4 t3o = make_float4(fmaf(2.f, go.x, -rt1o.x), fmaf(2.f, go.y, -rt1o.y),
                                 fmaf(2.f, go.z, -rt1o.z), fmaf(2.f, go.w, -rt1o.w));
        bA[n] = pk4(make_float4(fov * t3o.x, fov * t3o.y, fov * t3o.z, fov * t3o.w));
        *(uint2*)(bp + 5 * jstep) = pk4(t3o);           // j5 raw
        float4 t3i = make_float4(fmaf(fiv2, gi.x, -rt1o.x), fmaf(fiv2, gi.y, -rt1o.y),
                                 fmaf(fiv2, gi.z, -rt1o.z), fmaf(fiv2, gi.w, -rt1o.w));
        bB[n] = pk4(t3i);
        *(uint2*)(bp + 6 * jstep) = pk4(t3i);           // j6 raw
    }
    __syncthreads();
    // ph78: T4o = 2*sum(bA) - T2o ; T4i = fiv2*sum(bB) - T2o (quirk: both T2o)
    if (act) {
        float4 go = g8(bA, eo_s, e0o, e1o);
        float4 gi = g8(bB, eid_s, e0i, e1i);
        float4 t4o = make_float4(fmaf(2.f, go.x, -rt2o.x), fmaf(2.f, go.y, -rt2o.y),
                                 fmaf(2.f, go.z, -rt2o.z), fmaf(2.f, go.w, -rt2o.w));
        *(uint2*)(bp + 7 * jstep) = pk4(t4o);           // j7
        float4 t4i = make_float4(fmaf(fiv2, gi.x, -rt2o.x), fmaf(fiv2, gi.y, -rt2o.y),
                                 fmaf(fiv2, gi.z, -rt2o.z), fmaf(fiv2, gi.w, -rt2o.w));
        *(uint2*)(bp + 8 * jstep) = pk4(t4i);           // j8
    }
}

// ---------------- phase 2: GEMM [rchp,576]@[576,128] + gates + LN -> hnc (chunk-local) ----------------

__global__ __launch_bounds__(256, 4) void k_gemm(const u16* __restrict__ basis,
        const u16* __restrict__ wt, const void* __restrict__ bz, const void* __restrict__ bh,
        const void* __restrict__ lng, const void* __restrict__ lnb, u16* __restrict__ hnc,
        int rchp, int rchv, const int* __restrict__ flags) {
    union SM {
        struct { u16 A[8 * 128 * 4]; u16 B[128 * 40]; } st;
        float heh[128 * 65];
    };
    __shared__ SM sm;
    __shared__ float sMu[128], sRs[128];
    __shared__ float sBz[64], sBh[64], sG[64], sB2[64];

    const int tid = threadIdx.x;
    if (tid < 64) {
        const int f32m = flags[0];
        sBz[tid] = ldf(bz, tid, f32m); sBh[tid] = ldf(bh, tid, f32m);
        sG[tid] = ldf(lng, tid, f32m); sB2[tid] = ldf(lnb, tid, f32m);
    }
    const int lane = tid & 63, wv = tid >> 6;
    const int wr = wv >> 1, wc = wv & 1;
    const int m = lane & 15, q = lane >> 4;
    const int r0 = blockIdx.x * 128;

    f32x4_t acc[4][4];
    const f32x4_t zero = {0.f, 0.f, 0.f, 0.f};
    for (int mi = 0; mi < 4; ++mi)
        for (int ni = 0; ni < 4; ++ni) acc[mi][ni] = zero;

    for (int t = 0; t < 18; ++t) {
        const int j = t >> 1, hf = t & 1;
        #pragma unroll
        for (int p = 0; p < 2; ++p) {
            int lin = p * 256 + tid;
            int sbp = lin >> 6, rp = lin & 63;
            const u16* src = basis + ((size_t)((hf * 8 + sbp) * 9 + j) * rchp + r0 + rp * 2) * 4;
            *(uint4*)(&sm.st.A[lin * 8]) = *(const uint4*)src;
        }
        #pragma unroll
        for (int p = 0; p < 2; ++p) {
            int lin = p * 256 + tid;
            int c = lin >> 2, qq = lin & 3;
            const u16* src = wt + c * 576 + t * 32 + qq * 8;
            *(uint4*)(&sm.st.B[c * 40 + qq * 8]) = *(const uint4*)src;
        }
        __syncthreads();
        s16x8_t af[4], bfr[4];
        #pragma unroll
        for (int mi = 0; mi < 4; ++mi) {
            int r = wr * 64 + mi * 16 + m;
            s16x4_t lo = *(const s16x4_t*)&sm.st.A[(2 * q) * 512 + r * 4];
            s16x4_t hi = *(const s16x4_t*)&sm.st.A[(2 * q + 1) * 512 + r * 4];
            af[mi] = __builtin_shufflevector(lo, hi, 0, 1, 2, 3, 4, 5, 6, 7);
        }
        #pragma unroll
        for (int ni = 0; ni < 4; ++ni) {
            int c = (ni < 2) ? (wc * 32 + ni * 16 + m) : (64 + wc * 32 + (ni - 2) * 16 + m);
            bfr[ni] = *(const s16x8_t*)&sm.st.B[c * 40 + q * 8];
        }
        #pragma unroll
        for (int mi = 0; mi < 4; ++mi)
            #pragma unroll
            for (int ni = 0; ni < 4; ++ni)
                acc[mi][ni] = __builtin_amdgcn_mfma_f32_16x16x32_bf16(af[mi], bfr[ni], acc[mi][ni], 0, 0, 0);
        __syncthreads();
    }

    #pragma unroll
    for (int mi = 0; mi < 4; ++mi) {
        #pragma unroll
        for (int ni = 0; ni < 2; ++ni) {
            const int f = wc * 32 + ni * 16 + m;
            const float vbz = sBz[f], vbh = sBh[f];
            #pragma unroll
            for (int r = 0; r < 4; ++r) {
                const int rl = wr * 64 + mi * 16 + q * 4 + r;
                float zp = acc[mi][ni][r];
                float hp = acc[mi][ni + 2][r];
                zp = (zp == zp) ? zp : 0.f;
                hp = (hp == hp) ? hp : 0.f;
                zp = fminf(fmaxf(zp + vbz, -30.f), 30.f);
                hp = fminf(fmaxf(hp + vbh, -15.f), 15.f);
                const float z = __fdividef(1.f, 1.f + __expf(-zp));
                const float e2 = __expf(2.f * hp);
                const float ht = __fdividef(e2 - 1.f, e2 + 1.f);
                float h = (1.f - z) * ht;
                h = fmaxf(h, 0.f);
                sm.heh[rl * 65 + f] = h;
            }
        }
    }
    __syncthreads();
    if (tid < 128) {
        float sum = 0.f, ss = 0.f;
        #pragma unroll 8
        for (int f = 0; f < 64; ++f) {
            float v = sm.heh[tid * 65 + f];
            sum += v; ss += v * v;
        }
        float mu = sum * 0.015625f;
        float var = fmaxf(ss * 0.015625f - mu * mu, 0.f);
        sMu[tid] = mu;
        sRs[tid] = rsqrtf(var + 1e-5f);
    }
    __syncthreads();
    for (int idx = tid; idx < 128 * 64; idx += 256) {
        int rl = idx >> 6, f = idx & 63;
        if (r0 + rl < rchv) {
            float v = (sm.heh[rl * 65 + f] - sMu[rl]) * sRs[rl] * sG[f] + sB2[f];
            hnc[(size_t)(r0 + rl) * 64 + f] = f2bf(v);
        }
    }
}

// ---------------- phase 3: chunked final linear (accumulates into partials) ----------------

__global__ __launch_bounds__(256) void k_lin_chunk(const u16* __restrict__ hnc,
        const void* __restrict__ lw, float* __restrict__ partials, int s0, int chs,
        const int* __restrict__ flags) {
    const int tid = threadIdx.x;
    const int f32m = flags[0];
    float acc[NB][NC];
    #pragma unroll
    for (int b = 0; b < NB; ++b)
        #pragma unroll
        for (int c = 0; c < NC; ++c) acc[b][c] = 0.f;

    const int hi_s = s0 + chs - 1;
    for (int w = blockIdx.x * 256 + tid; w < TNF; w += LWG * 256) {
        const int t = w / 64000;
        int blo_n = s0 - t + 11;
        const int blo = (blo_n > 0) ? (blo_n / 12) : 0;
        const int bhi_n = hi_s - t;
        const int bhi = (bhi_n >= 0) ? (bhi_n / 12) : -1;
        if (bhi < blo) continue;
        float wvv[NC];
        if (f32m) {
            #pragma unroll
            for (int c = 0; c < NC; ++c) wvv[c] = ((const float*)lw)[(size_t)c * TNF + w];
        } else {
            #pragma unroll
            for (int c = 0; c < NC; ++c) wvv[c] = bf2f(((const u16*)lw)[(size_t)c * TNF + w]);
        }
        #pragma unroll
        for (int c = 0; c < NC; ++c) {
            float v = wvv[c];
            wvv[c] = (v == v && v > -1e30f && v < 1e30f) ? v : 0.f;
        }
        #pragma unroll
        for (int b = 0; b < NB; ++b) {
            if (b >= blo && b <= bhi) {
                const int sl = b * 12 + t - s0;
                const float h = bf2f(hnc[(size_t)sl * 64000 + (w - t * 64000)]);
                #pragma unroll
                for (int c = 0; c < NC; ++c) acc[b][c] = fmaf(h, wvv[c], acc[b][c]);
            }
        }
    }
    __shared__ float sRed[4][160];
    const int wvi = tid >> 6, lane = tid & 63;
    #pragma unroll
    for (int b = 0; b < NB; ++b)
        #pragma unroll
        for (int c = 0; c < NC; ++c) {
            float v = acc[b][c];
            #pragma unroll
            for (int off = 1; off < 64; off <<= 1) v += __shfl_xor(v, off, 64);
            if (lane == 0) sRed[wvi][b * NC + c] = v;
        }
    __syncthreads();
    if (tid < 160)
        partials[(size_t)blockIdx.x * 160 + tid] +=
            sRed[0][tid] + sRed[1][tid] + sRed[2][tid] + sRed[3][tid];
}

__global__ void k_red(const float* __restrict__ partials, const void* __restrict__ lb,
                      void* __restrict__ out, const int* __restrict__ flags) {
    const int o = threadIdx.x;
    const int f32m = flags[0];
    if (o < 160) {
        float s = ldf(lb, o % NC, f32m);
        #pragma unroll 8
        for (int wg = 0; wg < LWG; ++wg) s += partials[(size_t)wg * 160 + o];
        if (f32m) ((float*)out)[o] = s;
        else      ((u16*)out)[o] = f2bf(s);
    }
}

// ---------------- launch ----------------

extern "C" void kernel_launch(void* const* d_in, const int* in_sizes, int n_in,
                              void* d_out, int out_size, void* d_ws, size_t ws_size,
                              hipStream_t stream) {
    (void)in_sizes; (void)n_in; (void)out_size;
    const void* x   = d_in[0];
    const int*  ei  = (const int*)d_in[1];
    const void* Wz  = d_in[2];
    const void* bz  = d_in[3];
    const void* Wh  = d_in[6];
    const void* bh  = d_in[7];
    const void* lng = d_in[8];
    const void* lnb = d_in[9];
    const void* lw  = d_in[10];
    const void* lb  = d_in[11];

    char* ws = (char*)d_ws;
    size_t off = 0;
    auto alloc = [&](size_t bytes) -> void* {
        void* p = ws + off;
        off = (off + bytes + 255) & ~(size_t)255;
        return p;
    };
    int*   flags    = (int*)  alloc(64);
    u16*   wt       = (u16*)  alloc(128 * 576 * 2);
    int*   ints     = (int*)  alloc(4000 * 4);
    int*   ooffp    = (int*)  alloc(1024 * 4);
    int*   ioffp    = (int*)  alloc(1024 * 4);
    float* inv_o    = (float*)alloc(1000 * 4);
    float* inv_i    = (float*)alloc(1000 * 4);
    u16*   eo_s     = (u16*)  alloc((size_t)EPAD * 2);
    u16*   eid_s    = (u16*)  alloc((size_t)EPAD * 2);
    float* partials = (float*)alloc((size_t)LWG * 160 * 4);

    const int cand[] = {192, 96, 64, 48, 32, 24, 16, 12, 8, 6, 4, 3, 2, 1};
    int CHS = 1, RCHP = 1024;
    for (int ci = 0; ci < 14; ++ci) {
        int c = cand[ci];
        int rchp = ((c * NN + 127) / 128) * 128;
        size_t need = (size_t)16 * 9 * rchp * 8 + (size_t)c * NN * FF * 2 + 8192;
        if (off + need <= ws_size) { CHS = c; RCHP = rchp; break; }
    }
    u16* basis = (u16*)alloc((size_t)16 * 9 * RCHP * 8);
    u16* hnc   = (u16*)alloc((size_t)CHS * NN * FF * 2);

    int* deg_out = ints;
    int* deg_in  = ints + 1000;
    int* cur     = ints + 2000;

    k_detect<<<1, 64, 0, stream>>>((const u16*)x, ei, flags);
    k_zero<<<16, 256, 0, stream>>>(ints);
    k_zpart<<<(LWG * 160 + 255) / 256, 256, 0, stream>>>(partials);
    k_fille<<<(EPAD / 2 + 255) / 256, 256, 0, stream>>>(eo_s, eid_s);
    k_deg<<<(EE + 255) / 256, 256, 0, stream>>>(ei, ints, flags);
    k_scan<<<1, 1024, 0, stream>>>(deg_in, deg_out, ooffp, ioffp, inv_o, inv_i);
    k_fill<<<(EE + 255) / 256, 256, 0, stream>>>(ei, ooffp, ioffp, cur, eo_s, eid_s, flags);
    k_wt<<<288, 256, 0, stream>>>(Wz, Wh, wt, flags);
    const int nchunk = SS / CHS;
    for (int ch = 0; ch < nchunk; ++ch) {
        k_cheb<<<CHS * 16, 1024, 0, stream>>>(x, eo_s, ooffp, eid_s, ioffp, inv_o, inv_i,
                                              basis, ch * CHS, RCHP, flags, CHS);
        k_gemm<<<RCHP / 128, 256, 0, stream>>>(basis, wt, bz, bh, lng, lnb, hnc,
                                               RCHP, CHS * NN, flags);
        k_lin_chunk<<<LWG, 256, 0, stream>>>(hnc, lw, partials, ch * CHS, CHS, flags);
    }
    k_red<<<1, 256, 0, stream>>>(partials, lb, d_out, flags);
}

// Round 6
// 544.800 us; speedup vs baseline: 1.7352x; 1.0071x over previous
//
#include <hip/hip_runtime.h>

#define NN   1000
#define EE   16000
#define FF   64
#define SS   192
#define TNF  768000
#define NB   16
#define NC   10
#define LWG  256   // k_lin_chunk / partials width
#define EPAD 24576 // padded edge-list capacity (sum ceil(deg/8)*8 <= 23000)

typedef unsigned short u16;
typedef unsigned int   u32;
typedef float f32x4_t __attribute__((ext_vector_type(4)));
typedef short s16x4_t __attribute__((ext_vector_type(4)));
typedef short s16x8_t __attribute__((ext_vector_type(8)));

__device__ __forceinline__ float bf2f(u16 u) {
    return __uint_as_float(((u32)u) << 16);
}
__device__ __forceinline__ u16 f2bf(float f) {
    u32 u = __float_as_uint(f);
    u32 r = u + 0x7FFFu + ((u >> 16) & 1u);
    return (u16)(r >> 16);
}
// flag-dispatched scalar float load (f32m: 1 = fp32 array, 0 = bf16 array)
__device__ __forceinline__ float ldf(const void* p, size_t i, int f32m) {
    return f32m ? ((const float*)p)[i] : bf2f(((const u16*)p)[i]);
}

// pack float4 -> 4 bf16 in a uint2 (bit-identical to ushort4{f2bf(x..w)})
__device__ __forceinline__ uint2 pk4(float4 v) {
    uint2 p;
    p.x = (u32)f2bf(v.x) | ((u32)f2bf(v.y) << 16);
    p.y = (u32)f2bf(v.z) | ((u32)f2bf(v.w) << 16);
    return p;
}
// unpack low/high bf16 of a u32 word to f32
__device__ __forceinline__ float bl(u32 q) { return __uint_as_float(q << 16); }
__device__ __forceinline__ float bh(u32 q) { return __uint_as_float(q & 0xFFFF0000u); }

// async global->LDS 16B copy (dest must be wave-uniform base + lane*16)
__device__ __forceinline__ void gl_lds16(const void* src, void* dst) {
    __builtin_amdgcn_global_load_lds(
        (const __attribute__((address_space(1))) unsigned int*)src,
        (__attribute__((address_space(3))) unsigned int*)dst, 16, 0, 0);
}

// ---------------- dtype detection ----------------
__global__ void k_detect(const u16* __restrict__ x, const int* __restrict__ ei,
                         int* __restrict__ flags) {
    if (threadIdx.x == 0) {
        int good = 0;
        for (int i = 0; i < 256; i += 2) {
            u16 u = x[i];
            int e = (u >> 7) & 0xFF;
            if (u == 0 || (e >= 100 && e <= 140)) ++good;
        }
        flags[0] = (good < 96) ? 1 : 0;          // <75% plausible -> fp32
        int nz = 0;
        for (int i = 1; i < 64; i += 2) nz += (ei[i] != 0);
        flags[1] = (nz <= 4) ? 1 : 0;            // odd words all zero -> int64
    }
}

// ---------------- prep kernels ----------------

// merged: zero ints, zero partials, prefill padded edge lists with dummy 1000
__global__ void k_init(int* __restrict__ ints, float* __restrict__ partials,
                       u16* __restrict__ eo_s, u16* __restrict__ eid_s) {
    int i = blockIdx.x * 256 + threadIdx.x;
    if (i < 4000) ints[i] = 0;
    if (i < LWG * 160) partials[i] = 0.f;
    if (i < EPAD / 2) {
        ((u32*)eo_s)[i] = 0x03E803E8u;
        ((u32*)eid_s)[i] = 0x03E803E8u;
    }
}

__global__ void k_deg(const int* __restrict__ ei, int* __restrict__ deg,
                      const int* __restrict__ flags) {
    int e = blockIdx.x * 256 + threadIdx.x;
    const int sh = flags[1];
    if (e < EE) {
        int r = ei[(size_t)e << sh];
        int c = ei[(size_t)(EE + e) << sh];
        atomicAdd(&deg[r & 1023], 1);
        atomicAdd(&deg[NN + (c & 1023)], 1);
    }
}

// 8-padded CSR offsets: ooffp from ceil(deg_in/8)*8 (edges grouped by dst),
// ioffp from ceil(deg_out/8)*8 (edges grouped by src). Plus inverse degrees.
__global__ __launch_bounds__(1024) void k_scan(const int* __restrict__ deg_in,
        const int* __restrict__ deg_out, int* __restrict__ ooffp, int* __restrict__ ioffp,
        float* __restrict__ inv_o, float* __restrict__ inv_i) {
    __shared__ int sa[1024], sb2[1024];
    const int t = threadIdx.x;
    for (int pass = 0; pass < 2; ++pass) {
        const int* deg = pass ? deg_out : deg_in;
        int* dst_off = pass ? ioffp : ooffp;
        sa[t] = (t < NN) ? ((deg[t] + 7) & ~7) : 0;
        __syncthreads();
        int* src = sa; int* dst = sb2;
        for (int offn = 1; offn < 1024; offn <<= 1) {
            int v = src[t];
            if (t >= offn) v += src[t - offn];
            dst[t] = v;
            __syncthreads();
            int* tmp = src; src = dst; dst = tmp;
        }
        if (t == 0) dst_off[0] = 0;
        if (t < NN) dst_off[t + 1] = src[t];
        __syncthreads();
    }
    if (t < NN) {
        inv_o[t] = 1.0f / (float)max(deg_out[t], 1);
        inv_i[t] = 1.0f / (float)max(deg_in[t], 1);
    }
}

__global__ void k_fill(const int* __restrict__ ei, const int* __restrict__ ooffp,
        const int* __restrict__ ioffp, int* __restrict__ cur,
        u16* __restrict__ eo_s, u16* __restrict__ eid_s,
        const int* __restrict__ flags) {
    int e = blockIdx.x * 256 + threadIdx.x;
    const int sh = flags[1];
    if (e < EE) {
        int r = ei[(size_t)e << sh] & 1023;
        int c = ei[(size_t)(EE + e) << sh] & 1023;
        int po = ooffp[c] + atomicAdd(&cur[c], 1);       // group by dst
        eo_s[po] = (u16)r;
        int pi = ioffp[r] + atomicAdd(&cur[NN + r], 1);  // group by src
        eid_s[pi] = (u16)c;
    }
}

// Wt[col][kappa], kappa = j*64 + fi.  col<64 -> z (W_z), col>=64 -> h (W_h).
__global__ void k_wt(const void* __restrict__ Wz, const void* __restrict__ Wh,
                     u16* __restrict__ wt, const int* __restrict__ flags) {
    int idx = blockIdx.x * 256 + threadIdx.x;
    if (idx >= 128 * 576) return;
    const int f32m = flags[0];
    const int col = idx / 576;
    const int kk = idx - col * 576;
    const int j = kk >> 6, fi = kk & 63;
    const void* W = (col < 64) ? Wz : Wh;
    const int fo = col & 63;
    float v;
    if (j == 0) {
        v = ldf(W, (size_t)(0 * 128 + fi) * 64 + fo, f32m)
          + ldf(W, (size_t)(5 * 128 + fi) * 64 + fo, f32m);
    } else {
        const int d = (j & 1) ? 0 : 1;
        const int kq = (j + 1) >> 1;
        v = ldf(W, (size_t)((d * 5 + kq) * 128 + fi) * 64 + fo, f32m);
    }
    wt[col * 576 + kk] = f2bf(v);
}

// ---------------- phase 1: Chebyshev basis (UNCHANGED from R5 — control) ----------------
// basis: [sb(16)][j(9)][row(rchp)][f4(4)] bf16

__device__ __forceinline__ float4 g8(const uint2* __restrict__ S,
                                     const u16* __restrict__ lst, int e0, int e1) {
    float4 a = make_float4(0.f, 0.f, 0.f, 0.f);
    for (int e = e0; e < e1; e += 8) {
        uint4 w = *(const uint4*)(lst + e);   // 8 u16 indices, 16B aligned
        int i0 = w.x & 0xFFFF, i1 = w.x >> 16;
        int i2 = w.y & 0xFFFF, i3 = w.y >> 16;
        int i4 = w.z & 0xFFFF, i5 = w.z >> 16;
        int i6 = w.w & 0xFFFF, i7 = w.w >> 16;
        uint2 q0 = S[i0], q1 = S[i1], q2 = S[i2], q3 = S[i3];
        uint2 q4 = S[i4], q5 = S[i5], q6 = S[i6], q7 = S[i7];
        a.x += bl(q0.x) + bl(q1.x) + bl(q2.x) + bl(q3.x)
             + bl(q4.x) + bl(q5.x) + bl(q6.x) + bl(q7.x);
        a.y += bh(q0.x) + bh(q1.x) + bh(q2.x) + bh(q3.x)
             + bh(q4.x) + bh(q5.x) + bh(q6.x) + bh(q7.x);
        a.z += bl(q0.y) + bl(q1.y) + bl(q2.y) + bl(q3.y)
             + bl(q4.y) + bl(q5.y) + bl(q6.y) + bl(q7.y);
        a.w += bh(q0.y) + bh(q1.y) + bh(q2.y) + bh(q3.y)
             + bh(q4.y) + bh(q5.y) + bh(q6.y) + bh(q7.y);
    }
    return a;
}

__global__ __launch_bounds__(1024) void k_cheb(const void* __restrict__ xv_,
        const u16* __restrict__ eo_s, const int* __restrict__ ooffp,
        const u16* __restrict__ eid_s, const int* __restrict__ ioffp,
        const float* __restrict__ inv_o, const float* __restrict__ inv_i,
        u16* __restrict__ basis, int s0, int rchp,
        const int* __restrict__ flags, int chs) {
    __shared__ uint2 bXo[1024], bXi[1024], bA[1024], bB[1024];
    const int sb = blockIdx.x / chs;
    const int slocal = blockIdx.x - sb * chs;
    const int s = s0 + slocal;
    const int n = threadIdx.x;
    const bool act = (n < NN);
    const int f32m = flags[0];
    int e0o = 0, e1o = 0, e0i = 0, e1i = 0;
    float fiv = 0.f, fov = 0.f;
    const int row = slocal * NN + n;
    if (act) {
        e0o = ooffp[n]; e1o = ooffp[n + 1];
        e0i = ioffp[n]; e1i = ioffp[n + 1];
        fiv = inv_i[n];
        fov = inv_o[n];
    }
    const float fiv2 = 2.f * fiv;
    u16* const bp = basis + (size_t)(sb * 9) * rchp * 4 + (size_t)row * 4;
    const size_t jstep = (size_t)rchp * 4;   // u16s per j-plane
    float4 rx, rt1o, rt2o;
    if (n >= NN) {   // zero the dummy slots (1000..1023) in all buffers
        const uint2 z = make_uint2(0u, 0u);
        bXo[n] = z; bXi[n] = z; bA[n] = z; bB[n] = z;
    }
    if (act) {
        const size_t xoff = ((size_t)s * NN + n) * FF + sb * 4;
        if (f32m) {
            rx = *(const float4*)((const float*)xv_ + xoff);
        } else {
            ushort4 u = *(const ushort4*)((const u16*)xv_ + xoff);
            rx = make_float4(bf2f(u.x), bf2f(u.y), bf2f(u.z), bf2f(u.w));
        }
        bXi[n] = pk4(rx);
        bXo[n] = pk4(make_float4(fov * rx.x, fov * rx.y, fov * rx.z, fov * rx.w));
        *(uint2*)bp = pk4(rx);                          // j0 raw
    }
    __syncthreads();
    // ph12: T1o = sum(bXo) ; T1i = fiv * sum(bXi)
    if (act) {
        float4 go = g8(bXo, eo_s, e0o, e1o);
        float4 gi = g8(bXi, eid_s, e0i, e1i);
        rt1o = go;
        bA[n] = pk4(make_float4(fov * go.x, fov * go.y, fov * go.z, fov * go.w));
        *(uint2*)(bp + jstep) = pk4(go);                // j1 raw
        float4 t = make_float4(gi.x * fiv, gi.y * fiv, gi.z * fiv, gi.w * fiv);
        bB[n] = pk4(t);
        *(uint2*)(bp + 2 * jstep) = pk4(t);             // j2 raw
    }
    __syncthreads();
    // ph34: T2o = 2*sum(bA) - x ; T2i = fiv2*sum(bB) - x
    if (act) {
        float4 go = g8(bA, eo_s, e0o, e1o);
        float4 gi = g8(bB, eid_s, e0i, e1i);
        float4 t2o = make_float4(fmaf(2.f, go.x, -rx.x), fmaf(2.f, go.y, -rx.y),
                                 fmaf(2.f, go.z, -rx.z), fmaf(2.f, go.w, -rx.w));
        rt2o = t2o;
        bXo[n] = pk4(make_float4(fov * t2o.x, fov * t2o.y, fov * t2o.z, fov * t2o.w));
        *(uint2*)(bp + 3 * jstep) = pk4(t2o);           // j3 raw
        float4 t2i = make_float4(fmaf(fiv2, gi.x, -rx.x), fmaf(fiv2, gi.y, -rx.y),
                                 fmaf(fiv2, gi.z, -rx.z), fmaf(fiv2, gi.w, -rx.w));
        bXi[n] = pk4(t2i);
        *(uint2*)(bp + 4 * jstep) = pk4(t2i);           // j4 raw
    }
    __syncthreads();
    // ph56: T3o = 2*sum(bXo) - T1o ; T3i = fiv2*sum(bXi) - T1o (quirk: both T1o)
    if (act) {
        float4 go = g8(bXo, eo_s, e0o, e1o);
        float4 gi = g8(bXi, eid_s, e0i, e1i);
        float4 t3o = make_float4(fmaf(2.f, go.x, -rt1o.x), fmaf(2.f, go.y, -rt1o.y),
                                 fmaf(2.f, go.z, -rt1o.z), fmaf(2.f, go.w, -rt1o.w));
        bA[n] = pk4(make_float4(fov * t3o.x, fov * t3o.y, fov * t3o.z, fov * t3o.w));
        *(uint2*)(bp + 5 * jstep) = pk4(t3o);           // j5 raw
        float4 t3i = make_float4(fmaf(fiv2, gi.x, -rt1o.x), fmaf(fiv2, gi.y, -rt1o.y),
                                 fmaf(fiv2, gi.z, -rt1o.z), fmaf(fiv2, gi.w, -rt1o.w));
        bB[n] = pk4(t3i);
        *(uint2*)(bp + 6 * jstep) = pk4(t3i);           // j6 raw
    }
    __syncthreads();
    // ph78: T4o = 2*sum(bA) - T2o ; T4i = fiv2*sum(bB) - T2o (quirk: both T2o)
    if (act) {
        float4 go = g8(bA, eo_s, e0o, e1o);
        float4 gi = g8(bB, eid_s, e0i, e1i);
        float4 t4o = make_float4(fmaf(2.f, go.x, -rt2o.x), fmaf(2.f, go.y, -rt2o.y),
                                 fmaf(2.f, go.z, -rt2o.z), fmaf(2.f, go.w, -rt2o.w));
        *(uint2*)(bp + 7 * jstep) = pk4(t4o);           // j7
        float4 t4i = make_float4(fmaf(fiv2, gi.x, -rt2o.x), fmaf(fiv2, gi.y, -rt2o.y),
                                 fmaf(fiv2, gi.z, -rt2o.z), fmaf(fiv2, gi.w, -rt2o.w));
        *(uint2*)(bp + 8 * jstep) = pk4(t4i);           // j8
    }
}

// ---------------- phase 2: GEMM [rchp,576]@[576,128] + gates + LN -> hnc ----------------
// Staging now via global_load_lds width=16 (no VGPR round-trip).
// A LDS layout unchanged (dest byte = lin*16, already linear).
// B LDS layout: linear 512 slots x 16B; fragment (c,qq) lives at slot
//   c*4 + ((qq ^ c ^ (c>>2)) & 3)  — invertible swizzle so the 16 lanes of a
//   q-group hit 8 distinct bank-starts (uniform, conflict-free b128 reads).

__global__ __launch_bounds__(256, 4) void k_gemm(const u16* __restrict__ basis,
        const u16* __restrict__ wt, const void* __restrict__ bz, const void* __restrict__ bh_,
        const void* __restrict__ lng, const void* __restrict__ lnb, u16* __restrict__ hnc,
        int rchp, int rchv, const int* __restrict__ flags) {
    union SM {
        struct { u16 A[512 * 8]; u16 B[512 * 8]; } st;   // 8KB + 8KB
        float heh[128 * 65];
    };
    __shared__ SM sm;
    __shared__ float sMu[128], sRs[128];
    __shared__ float sBz[64], sBh[64], sG[64], sB2[64];

    const int tid = threadIdx.x;
    if (tid < 64) {
        const int f32m = flags[0];
        sBz[tid] = ldf(bz, tid, f32m); sBh[tid] = ldf(bh_, tid, f32m);
        sG[tid] = ldf(lng, tid, f32m); sB2[tid] = ldf(lnb, tid, f32m);
    }
    const int lane = tid & 63, wv = tid >> 6;
    const int wr = wv >> 1, wc = wv & 1;
    const int m = lane & 15, q = lane >> 4;
    const int r0 = blockIdx.x * 128;

    f32x4_t acc[4][4];
    const f32x4_t zero = {0.f, 0.f, 0.f, 0.f};
    for (int mi = 0; mi < 4; ++mi)
        for (int ni = 0; ni < 4; ++ni) acc[mi][ni] = zero;

    for (int t = 0; t < 18; ++t) {
        const int j = t >> 1, hf = t & 1;
        #pragma unroll
        for (int p = 0; p < 2; ++p) {
            int lin = p * 256 + tid;
            int sbp = lin >> 6, rp = lin & 63;
            const u16* src = basis + ((size_t)((hf * 8 + sbp) * 9 + j) * rchp + r0 + rp * 2) * 4;
            gl_lds16(src, &sm.st.A[lin * 8]);
        }
        #pragma unroll
        for (int p = 0; p < 2; ++p) {
            int lin = p * 256 + tid;
            int c = lin >> 2;
            int qq = ((lin & 3) ^ c ^ (c >> 2)) & 3;
            gl_lds16(wt + c * 576 + t * 32 + qq * 8, &sm.st.B[lin * 8]);
        }
        __syncthreads();
        s16x8_t af[4], bfr[4];
        #pragma unroll
        for (int mi = 0; mi < 4; ++mi) {
            int r = wr * 64 + mi * 16 + m;
            s16x4_t lo = *(const s16x4_t*)&sm.st.A[(2 * q) * 512 + r * 4];
            s16x4_t hi = *(const s16x4_t*)&sm.st.A[(2 * q + 1) * 512 + r * 4];
            af[mi] = __builtin_shufflevector(lo, hi, 0, 1, 2, 3, 4, 5, 6, 7);
        }
        #pragma unroll
        for (int ni = 0; ni < 4; ++ni) {
            int c = (ni < 2) ? (wc * 32 + ni * 16 + m) : (64 + wc * 32 + (ni - 2) * 16 + m);
            int slot = (q ^ c ^ (c >> 2)) & 3;
            bfr[ni] = *(const s16x8_t*)&sm.st.B[(c * 4 + slot) * 8];
        }
        #pragma unroll
        for (int mi = 0; mi < 4; ++mi)
            #pragma unroll
            for (int ni = 0; ni < 4; ++ni)
                acc[mi][ni] = __builtin_amdgcn_mfma_f32_16x16x32_bf16(af[mi], bfr[ni], acc[mi][ni], 0, 0, 0);
        __syncthreads();
    }

    #pragma unroll
    for (int mi = 0; mi < 4; ++mi) {
        #pragma unroll
        for (int ni = 0; ni < 2; ++ni) {
            const int f = wc * 32 + ni * 16 + m;
            const float vbz = sBz[f], vbh = sBh[f];
            #pragma unroll
            for (int r = 0; r < 4; ++r) {
                const int rl = wr * 64 + mi * 16 + q * 4 + r;
                float zp = acc[mi][ni][r];
                float hp = acc[mi][ni + 2][r];
                zp = (zp == zp) ? zp : 0.f;
                hp = (hp == hp) ? hp : 0.f;
                zp = fminf(fmaxf(zp + vbz, -30.f), 30.f);
                hp = fminf(fmaxf(hp + vbh, -15.f), 15.f);
                const float z = __fdividef(1.f, 1.f + __expf(-zp));
                const float e2 = __expf(2.f * hp);
                const float ht = __fdividef(e2 - 1.f, e2 + 1.f);
                float h = (1.f - z) * ht;
                h = fmaxf(h, 0.f);
                sm.heh[rl * 65 + f] = h;
            }
        }
    }
    __syncthreads();
    if (tid < 128) {
        float sum = 0.f, ss = 0.f;
        #pragma unroll 8
        for (int f = 0; f < 64; ++f) {
            float v = sm.heh[tid * 65 + f];
            sum += v; ss += v * v;
        }
        float mu = sum * 0.015625f;
        float var = fmaxf(ss * 0.015625f - mu * mu, 0.f);
        sMu[tid] = mu;
        sRs[tid] = rsqrtf(var + 1e-5f);
    }
    __syncthreads();
    for (int idx = tid; idx < 128 * 64; idx += 256) {
        int rl = idx >> 6, f = idx & 63;
        if (r0 + rl < rchv) {
            float v = (sm.heh[rl * 65 + f] - sMu[rl]) * sRs[rl] * sG[f] + sB2[f];
            hnc[(size_t)(r0 + rl) * 64 + f] = f2bf(v);
        }
    }
}

// ---------------- phase 3: chunked final linear (accumulates into partials) ----------------

__global__ __launch_bounds__(256) void k_lin_chunk(const u16* __restrict__ hnc,
        const void* __restrict__ lw, float* __restrict__ partials, int s0, int chs,
        const int* __restrict__ flags) {
    const int tid = threadIdx.x;
    const int f32m = flags[0];
    float acc[NB][NC];
    #pragma unroll
    for (int b = 0; b < NB; ++b)
        #pragma unroll
        for (int c = 0; c < NC; ++c) acc[b][c] = 0.f;

    const int hi_s = s0 + chs - 1;
    for (int w = blockIdx.x * 256 + tid; w < TNF; w += LWG * 256) {
        const int t = w / 64000;
        int blo_n = s0 - t + 11;
        const int blo = (blo_n > 0) ? (blo_n / 12) : 0;
        const int bhi_n = hi_s - t;
        const int bhi = (bhi_n >= 0) ? (bhi_n / 12) : -1;
        if (bhi < blo) continue;
        float wvv[NC];
        if (f32m) {
            #pragma unroll
            for (int c = 0; c < NC; ++c) wvv[c] = ((const float*)lw)[(size_t)c * TNF + w];
        } else {
            #pragma unroll
            for (int c = 0; c < NC; ++c) wvv[c] = bf2f(((const u16*)lw)[(size_t)c * TNF + w]);
        }
        #pragma unroll
        for (int c = 0; c < NC; ++c) {
            float v = wvv[c];
            wvv[c] = (v == v && v > -1e30f && v < 1e30f) ? v : 0.f;
        }
        #pragma unroll
        for (int b = 0; b < NB; ++b) {
            if (b >= blo && b <= bhi) {
                const int sl = b * 12 + t - s0;
                const float h = bf2f(hnc[(size_t)sl * 64000 + (w - t * 64000)]);
                #pragma unroll
                for (int c = 0; c < NC; ++c) acc[b][c] = fmaf(h, wvv[c], acc[b][c]);
            }
        }
    }
    __shared__ float sRed[4][160];
    const int wvi = tid >> 6, lane = tid & 63;
    #pragma unroll
    for (int b = 0; b < NB; ++b)
        #pragma unroll
        for (int c = 0; c < NC; ++c) {
            float v = acc[b][c];
            #pragma unroll
            for (int off = 1; off < 64; off <<= 1) v += __shfl_xor(v, off, 64);
            if (lane == 0) sRed[wvi][b * NC + c] = v;
        }
    __syncthreads();
    if (tid < 160)
        partials[(size_t)blockIdx.x * 160 + tid] +=
            sRed[0][tid] + sRed[1][tid] + sRed[2][tid] + sRed[3][tid];
}

__global__ void k_red(const float* __restrict__ partials, const void* __restrict__ lb,
                      void* __restrict__ out, const int* __restrict__ flags) {
    const int o = threadIdx.x;
    const int f32m = flags[0];
    if (o < 160) {
        float s = ldf(lb, o % NC, f32m);
        #pragma unroll 8
        for (int wg = 0; wg < LWG; ++wg) s += partials[(size_t)wg * 160 + o];
        if (f32m) ((float*)out)[o] = s;
        else      ((u16*)out)[o] = f2bf(s);
    }
}

// ---------------- launch ----------------

extern "C" void kernel_launch(void* const* d_in, const int* in_sizes, int n_in,
                              void* d_out, int out_size, void* d_ws, size_t ws_size,
                              hipStream_t stream) {
    (void)in_sizes; (void)n_in; (void)out_size;
    const void* x   = d_in[0];
    const int*  ei  = (const int*)d_in[1];
    const void* Wz  = d_in[2];
    const void* bz  = d_in[3];
    const void* Wh  = d_in[6];
    const void* bh  = d_in[7];
    const void* lng = d_in[8];
    const void* lnb = d_in[9];
    const void* lw  = d_in[10];
    const void* lb  = d_in[11];

    char* ws = (char*)d_ws;
    size_t off = 0;
    auto alloc = [&](size_t bytes) -> void* {
        void* p = ws + off;
        off = (off + bytes + 255) & ~(size_t)255;
        return p;
    };
    int*   flags    = (int*)  alloc(64);
    u16*   wt       = (u16*)  alloc(128 * 576 * 2);
    int*   ints     = (int*)  alloc(4000 * 4);
    int*   ooffp    = (int*)  alloc(1024 * 4);
    int*   ioffp    = (int*)  alloc(1024 * 4);
    float* inv_o    = (float*)alloc(1000 * 4);
    float* inv_i    = (float*)alloc(1000 * 4);
    u16*   eo_s     = (u16*)  alloc((size_t)EPAD * 2);
    u16*   eid_s    = (u16*)  alloc((size_t)EPAD * 2);
    float* partials = (float*)alloc((size_t)LWG * 160 * 4);

    const int cand[] = {192, 96, 64, 48, 32, 24, 16, 12, 8, 6, 4, 3, 2, 1};
    int CHS = 1, RCHP = 1024;
    for (int ci = 0; ci < 14; ++ci) {
        int c = cand[ci];
        int rchp = ((c * NN + 127) / 128) * 128;
        size_t need = (size_t)16 * 9 * rchp * 8 + (size_t)c * NN * FF * 2 + 8192;
        if (off + need <= ws_size) { CHS = c; RCHP = rchp; break; }
    }
    u16* basis = (u16*)alloc((size_t)16 * 9 * RCHP * 8);
    u16* hnc   = (u16*)alloc((size_t)CHS * NN * FF * 2);

    int* deg_out = ints;
    int* deg_in  = ints + 1000;
    int* cur     = ints + 2000;

    k_detect<<<1, 64, 0, stream>>>((const u16*)x, ei, flags);
    k_init<<<160, 256, 0, stream>>>(ints, partials, eo_s, eid_s);
    k_deg<<<(EE + 255) / 256, 256, 0, stream>>>(ei, ints, flags);
    k_scan<<<1, 1024, 0, stream>>>(deg_in, deg_out, ooffp, ioffp, inv_o, inv_i);
    k_fill<<<(EE + 255) / 256, 256, 0, stream>>>(ei, ooffp, ioffp, cur, eo_s, eid_s, flags);
    k_wt<<<288, 256, 0, stream>>>(Wz, Wh, wt, flags);
    const int nchunk = SS / CHS;
    for (int ch = 0; ch < nchunk; ++ch) {
        k_cheb<<<CHS * 16, 1024, 0, stream>>>(x, eo_s, ooffp, eid_s, ioffp, inv_o, inv_i,
                                              basis, ch * CHS, RCHP, flags, CHS);
        k_gemm<<<RCHP / 128, 256, 0, stream>>>(basis, wt, bz, bh, lng, lnb, hnc,
                                               RCHP, CHS * NN, flags);
        k_lin_chunk<<<LWG, 256, 0, stream>>>(hnc, lw, partials, ch * CHS, CHS, flags);
    }
    k_red<<<1, 256, 0, stream>>>(partials, lb, d_out, flags);
}

// Round 7
// 537.156 us; speedup vs baseline: 1.7599x; 1.0142x over previous
//
#include <hip/hip_runtime.h>

#define NN   1000
#define EE   16000
#define FF   64
#define SS   192
#define TNF  768000
#define NB   16
#define NC   10
#define LWG2 1024  // k_lin_chunk grid (4 blocks/CU)
#define EPAD 24576 // padded edge-list capacity (sum ceil(deg/8)*8 <= 23000)

typedef unsigned short u16;
typedef unsigned int   u32;
typedef float f32x4_t __attribute__((ext_vector_type(4)));
typedef short s16x4_t __attribute__((ext_vector_type(4)));
typedef short s16x8_t __attribute__((ext_vector_type(8)));

__device__ __forceinline__ float bf2f(u16 u) {
    return __uint_as_float(((u32)u) << 16);
}
__device__ __forceinline__ u16 f2bf(float f) {
    u32 u = __float_as_uint(f);
    u32 r = u + 0x7FFFu + ((u >> 16) & 1u);
    return (u16)(r >> 16);
}
// flag-dispatched scalar float load (f32m: 1 = fp32 array, 0 = bf16 array)
__device__ __forceinline__ float ldf(const void* p, size_t i, int f32m) {
    return f32m ? ((const float*)p)[i] : bf2f(((const u16*)p)[i]);
}

// pack float4 -> 4 bf16 in a uint2 (bit-identical to ushort4{f2bf(x..w)})
__device__ __forceinline__ uint2 pk4(float4 v) {
    uint2 p;
    p.x = (u32)f2bf(v.x) | ((u32)f2bf(v.y) << 16);
    p.y = (u32)f2bf(v.z) | ((u32)f2bf(v.w) << 16);
    return p;
}
// unpack low/high bf16 of a u32 word to f32
__device__ __forceinline__ float bl(u32 q) { return __uint_as_float(q << 16); }
__device__ __forceinline__ float bh(u32 q) { return __uint_as_float(q & 0xFFFF0000u); }

// async global->LDS 16B copy (dest must be wave-uniform base + lane*16)
__device__ __forceinline__ void gl_lds16(const void* src, void* dst) {
    __builtin_amdgcn_global_load_lds(
        (const __attribute__((address_space(1))) unsigned int*)src,
        (__attribute__((address_space(3))) unsigned int*)dst, 16, 0, 0);
}

// ---------------- merged prep: detect + zero + edge-list prefill ----------------
__global__ void k_pre(const u16* __restrict__ x, const int* __restrict__ ei,
                      int* __restrict__ flags, int* __restrict__ ints,
                      float* __restrict__ obuf, u16* __restrict__ eo_s,
                      u16* __restrict__ eid_s) {
    const int i = blockIdx.x * 256 + threadIdx.x;
    if (blockIdx.x == 0 && threadIdx.x < 64) {   // wave 0: parallel dtype detect
        const int lane = threadIdx.x;
        u16 u1 = x[2 * lane], u2 = x[2 * (lane + 64)];
        int e1 = (u1 >> 7) & 0xFF, e2 = (u2 >> 7) & 0xFF;
        int ok1 = (u1 == 0 || (e1 >= 100 && e1 <= 140)) ? 1 : 0;
        int ok2 = (u2 == 0 || (e2 >= 100 && e2 <= 140)) ? 1 : 0;
        unsigned long long b1 = __ballot(ok1), b2 = __ballot(ok2);
        int nzf = (lane < 32 && ei[2 * lane + 1] != 0) ? 1 : 0;
        unsigned long long b3 = __ballot(nzf);
        if (lane == 0) {
            int good = __popcll(b1) + __popcll(b2);
            flags[0] = (good < 96) ? 1 : 0;           // <75% plausible -> fp32
            flags[1] = (__popcll(b3) <= 4) ? 1 : 0;   // odd words all zero -> int64
        }
    }
    if (i < 4000) ints[i] = 0;
    if (i < 160) obuf[i] = 0.f;
    if (i < EPAD / 2) {
        ((u32*)eo_s)[i] = 0x03E803E8u;
        ((u32*)eid_s)[i] = 0x03E803E8u;
    }
}

__global__ void k_deg(const int* __restrict__ ei, int* __restrict__ deg,
                      const int* __restrict__ flags) {
    int e = blockIdx.x * 256 + threadIdx.x;
    const int sh = flags[1];
    if (e < EE) {
        int r = ei[(size_t)e << sh];
        int c = ei[(size_t)(EE + e) << sh];
        atomicAdd(&deg[r & 1023], 1);
        atomicAdd(&deg[NN + (c & 1023)], 1);
    }
}

// 8-padded CSR offsets + inverse degrees
__global__ __launch_bounds__(1024) void k_scan(const int* __restrict__ deg_in,
        const int* __restrict__ deg_out, int* __restrict__ ooffp, int* __restrict__ ioffp,
        float* __restrict__ inv_o, float* __restrict__ inv_i) {
    __shared__ int sa[1024], sb2[1024];
    const int t = threadIdx.x;
    for (int pass = 0; pass < 2; ++pass) {
        const int* deg = pass ? deg_out : deg_in;
        int* dst_off = pass ? ioffp : ooffp;
        sa[t] = (t < NN) ? ((deg[t] + 7) & ~7) : 0;
        __syncthreads();
        int* src = sa; int* dst = sb2;
        for (int offn = 1; offn < 1024; offn <<= 1) {
            int v = src[t];
            if (t >= offn) v += src[t - offn];
            dst[t] = v;
            __syncthreads();
            int* tmp = src; src = dst; dst = tmp;
        }
        if (t == 0) dst_off[0] = 0;
        if (t < NN) dst_off[t + 1] = src[t];
        __syncthreads();
    }
    if (t < NN) {
        inv_o[t] = 1.0f / (float)max(deg_out[t], 1);
        inv_i[t] = 1.0f / (float)max(deg_in[t], 1);
    }
}

__global__ void k_fill(const int* __restrict__ ei, const int* __restrict__ ooffp,
        const int* __restrict__ ioffp, int* __restrict__ cur,
        u16* __restrict__ eo_s, u16* __restrict__ eid_s,
        const int* __restrict__ flags) {
    int e = blockIdx.x * 256 + threadIdx.x;
    const int sh = flags[1];
    if (e < EE) {
        int r = ei[(size_t)e << sh] & 1023;
        int c = ei[(size_t)(EE + e) << sh] & 1023;
        int po = ooffp[c] + atomicAdd(&cur[c], 1);       // group by dst
        eo_s[po] = (u16)r;
        int pi = ioffp[r] + atomicAdd(&cur[NN + r], 1);  // group by src
        eid_s[pi] = (u16)c;
    }
}

// Wt[col][kappa], kappa = j*64 + fi.  col<64 -> z (W_z), col>=64 -> h (W_h).
__global__ void k_wt(const void* __restrict__ Wz, const void* __restrict__ Wh,
                     u16* __restrict__ wt, const int* __restrict__ flags) {
    int idx = blockIdx.x * 256 + threadIdx.x;
    if (idx >= 128 * 576) return;
    const int f32m = flags[0];
    const int col = idx / 576;
    const int kk = idx - col * 576;
    const int j = kk >> 6, fi = kk & 63;
    const void* W = (col < 64) ? Wz : Wh;
    const int fo = col & 63;
    float v;
    if (j == 0) {
        v = ldf(W, (size_t)(0 * 128 + fi) * 64 + fo, f32m)
          + ldf(W, (size_t)(5 * 128 + fi) * 64 + fo, f32m);
    } else {
        const int d = (j & 1) ? 0 : 1;
        const int kq = (j + 1) >> 1;
        v = ldf(W, (size_t)((d * 5 + kq) * 128 + fi) * 64 + fo, f32m);
    }
    wt[col * 576 + kk] = f2bf(v);
}

// ---------------- phase 1: Chebyshev basis (UNCHANGED — control) ----------------
// basis: [sb(16)][j(9)][row(rchp)][f4(4)] bf16

__device__ __forceinline__ float4 g8(const uint2* __restrict__ S,
                                     const u16* __restrict__ lst, int e0, int e1) {
    float4 a = make_float4(0.f, 0.f, 0.f, 0.f);
    for (int e = e0; e < e1; e += 8) {
        uint4 w = *(const uint4*)(lst + e);   // 8 u16 indices, 16B aligned
        int i0 = w.x & 0xFFFF, i1 = w.x >> 16;
        int i2 = w.y & 0xFFFF, i3 = w.y >> 16;
        int i4 = w.z & 0xFFFF, i5 = w.z >> 16;
        int i6 = w.w & 0xFFFF, i7 = w.w >> 16;
        uint2 q0 = S[i0], q1 = S[i1], q2 = S[i2], q3 = S[i3];
        uint2 q4 = S[i4], q5 = S[i5], q6 = S[i6], q7 = S[i7];
        a.x += bl(q0.x) + bl(q1.x) + bl(q2.x) + bl(q3.x)
             + bl(q4.x) + bl(q5.x) + bl(q6.x) + bl(q7.x);
        a.y += bh(q0.x) + bh(q1.x) + bh(q2.x) + bh(q3.x)
             + bh(q4.x) + bh(q5.x) + bh(q6.x) + bh(q7.x);
        a.z += bl(q0.y) + bl(q1.y) + bl(q2.y) + bl(q3.y)
             + bl(q4.y) + bl(q5.y) + bl(q6.y) + bl(q7.y);
        a.w += bh(q0.y) + bh(q1.y) + bh(q2.y) + bh(q3.y)
             + bh(q4.y) + bh(q5.y) + bh(q6.y) + bh(q7.y);
    }
    return a;
}

__global__ __launch_bounds__(1024) void k_cheb(const void* __restrict__ xv_,
        const u16* __restrict__ eo_s, const int* __restrict__ ooffp,
        const u16* __restrict__ eid_s, const int* __restrict__ ioffp,
        const float* __restrict__ inv_o, const float* __restrict__ inv_i,
        u16* __restrict__ basis, int s0, int rchp,
        const int* __restrict__ flags, int chs) {
    __shared__ uint2 bXo[1024], bXi[1024], bA[1024], bB[1024];
    const int sb = blockIdx.x / chs;
    const int slocal = blockIdx.x - sb * chs;
    const int s = s0 + slocal;
    const int n = threadIdx.x;
    const bool act = (n < NN);
    const int f32m = flags[0];
    int e0o = 0, e1o = 0, e0i = 0, e1i = 0;
    float fiv = 0.f, fov = 0.f;
    const int row = slocal * NN + n;
    if (act) {
        e0o = ooffp[n]; e1o = ooffp[n + 1];
        e0i = ioffp[n]; e1i = ioffp[n + 1];
        fiv = inv_i[n];
        fov = inv_o[n];
    }
    const float fiv2 = 2.f * fiv;
    u16* const bp = basis + (size_t)(sb * 9) * rchp * 4 + (size_t)row * 4;
    const size_t jstep = (size_t)rchp * 4;   // u16s per j-plane
    float4 rx, rt1o, rt2o;
    if (n >= NN) {   // zero the dummy slots (1000..1023) in all buffers
        const uint2 z = make_uint2(0u, 0u);
        bXo[n] = z; bXi[n] = z; bA[n] = z; bB[n] = z;
    }
    if (act) {
        const size_t xoff = ((size_t)s * NN + n) * FF + sb * 4;
        if (f32m) {
            rx = *(const float4*)((const float*)xv_ + xoff);
        } else {
            ushort4 u = *(const ushort4*)((const u16*)xv_ + xoff);
            rx = make_float4(bf2f(u.x), bf2f(u.y), bf2f(u.z), bf2f(u.w));
        }
        bXi[n] = pk4(rx);
        bXo[n] = pk4(make_float4(fov * rx.x, fov * rx.y, fov * rx.z, fov * rx.w));
        *(uint2*)bp = pk4(rx);                          // j0 raw
    }
    __syncthreads();
    // ph12: T1o = sum(bXo) ; T1i = fiv * sum(bXi)
    if (act) {
        float4 go = g8(bXo, eo_s, e0o, e1o);
        float4 gi = g8(bXi, eid_s, e0i, e1i);
        rt1o = go;
        bA[n] = pk4(make_float4(fov * go.x, fov * go.y, fov * go.z, fov * go.w));
        *(uint2*)(bp + jstep) = pk4(go);                // j1 raw
        float4 t = make_float4(gi.x * fiv, gi.y * fiv, gi.z * fiv, gi.w * fiv);
        bB[n] = pk4(t);
        *(uint2*)(bp + 2 * jstep) = pk4(t);             // j2 raw
    }
    __syncthreads();
    // ph34: T2o = 2*sum(bA) - x ; T2i = fiv2*sum(bB) - x
    if (act) {
        float4 go = g8(bA, eo_s, e0o, e1o);
        float4 gi = g8(bB, eid_s, e0i, e1i);
        float4 t2o = make_float4(fmaf(2.f, go.x, -rx.x), fmaf(2.f, go.y, -rx.y),
                                 fmaf(2.f, go.z, -rx.z), fmaf(2.f, go.w, -rx.w));
        rt2o = t2o;
        bXo[n] = pk4(make_float4(fov * t2o.x, fov * t2o.y, fov * t2o.z, fov * t2o.w));
        *(uint2*)(bp + 3 * jstep) = pk4(t2o);           // j3 raw
        float4 t2i = make_float4(fmaf(fiv2, gi.x, -rx.x), fmaf(fiv2, gi.y, -rx.y),
                                 fmaf(fiv2, gi.z, -rx.z), fmaf(fiv2, gi.w, -rx.w));
        bXi[n] = pk4(t2i);
        *(uint2*)(bp + 4 * jstep) = pk4(t2i);           // j4 raw
    }
    __syncthreads();
    // ph56: T3o = 2*sum(bXo) - T1o ; T3i = fiv2*sum(bXi) - T1o (quirk: both T1o)
    if (act) {
        float4 go = g8(bXo, eo_s, e0o, e1o);
        float4 gi = g8(bXi, eid_s, e0i, e1i);
        float4 t3o = make_float4(fmaf(2.f, go.x, -rt1o.x), fmaf(2.f, go.y, -rt1o.y),
                                 fmaf(2.f, go.z, -rt1o.z), fmaf(2.f, go.w, -rt1o.w));
        bA[n] = pk4(make_float4(fov * t3o.x, fov * t3o.y, fov * t3o.z, fov * t3o.w));
        *(uint2*)(bp + 5 * jstep) = pk4(t3o);           // j5 raw
        float4 t3i = make_float4(fmaf(fiv2, gi.x, -rt1o.x), fmaf(fiv2, gi.y, -rt1o.y),
                                 fmaf(fiv2, gi.z, -rt1o.z), fmaf(fiv2, gi.w, -rt1o.w));
        bB[n] = pk4(t3i);
        *(uint2*)(bp + 6 * jstep) = pk4(t3i);           // j6 raw
    }
    __syncthreads();
    // ph78: T4o = 2*sum(bA) - T2o ; T4i = fiv2*sum(bB) - T2o (quirk: both T2o)
    if (act) {
        float4 go = g8(bA, eo_s, e0o, e1o);
        float4 gi = g8(bB, eid_s, e0i, e1i);
        float4 t4o = make_float4(fmaf(2.f, go.x, -rt2o.x), fmaf(2.f, go.y, -rt2o.y),
                                 fmaf(2.f, go.z, -rt2o.z), fmaf(2.f, go.w, -rt2o.w));
        *(uint2*)(bp + 7 * jstep) = pk4(t4o);           // j7
        float4 t4i = make_float4(fmaf(fiv2, gi.x, -rt2o.x), fmaf(fiv2, gi.y, -rt2o.y),
                                 fmaf(fiv2, gi.z, -rt2o.z), fmaf(fiv2, gi.w, -rt2o.w));
        *(uint2*)(bp + 8 * jstep) = pk4(t4i);           // j8
    }
}

// ---------------- phase 2: GEMM + gates + LN -> hnc ----------------
// LDS double-buffered staging (free: 2x16KB unions inside heh's 33KB) ->
// one barrier per K-step; gl_lds prefetch of t+1 hides under MFMA of t.
// Hazard audit: stage(t+1,buf^1) issued after barrier(t); ds_reads(t,buf) are
// consumed by MFMA(t) before barrier(t+1); stage(t+2,buf) issues after
// barrier(t+1) on every wave -> no overlap with reads of t. vmcnt drained by
// the compiler-emitted waitcnt at each __syncthreads.

__global__ __launch_bounds__(256, 4) void k_gemm(const u16* __restrict__ basis,
        const u16* __restrict__ wt, const void* __restrict__ bz, const void* __restrict__ bh_,
        const void* __restrict__ lng, const void* __restrict__ lnb, u16* __restrict__ hnc,
        int rchp, int rchv, const int* __restrict__ flags) {
    union SM {
        struct { u16 A[2][4096]; u16 B[2][4096]; } st;   // 2 x (8KB+8KB)
        float heh[128 * 65];
    };
    __shared__ SM sm;
    __shared__ float sMu[128], sRs[128];
    __shared__ float sBz[64], sBh[64], sG[64], sB2[64];

    const int tid = threadIdx.x;
    if (tid < 64) {
        const int f32m = flags[0];
        sBz[tid] = ldf(bz, tid, f32m); sBh[tid] = ldf(bh_, tid, f32m);
        sG[tid] = ldf(lng, tid, f32m); sB2[tid] = ldf(lnb, tid, f32m);
    }
    const int lane = tid & 63, wv = tid >> 6;
    const int wr = wv >> 1, wc = wv & 1;
    const int m = lane & 15, q = lane >> 4;
    const int r0 = blockIdx.x * 128;

    f32x4_t acc[4][4];
    const f32x4_t zero = {0.f, 0.f, 0.f, 0.f};
    for (int mi = 0; mi < 4; ++mi)
        for (int ni = 0; ni < 4; ++ni) acc[mi][ni] = zero;

    auto stage = [&](int bb, int t) {
        const int j = t >> 1, hf = t & 1;
        #pragma unroll
        for (int p = 0; p < 2; ++p) {
            int lin = p * 256 + tid;
            int sbp = lin >> 6, rp = lin & 63;
            const u16* src = basis + ((size_t)((hf * 8 + sbp) * 9 + j) * rchp + r0 + rp * 2) * 4;
            gl_lds16(src, &sm.st.A[bb][lin * 8]);
        }
        #pragma unroll
        for (int p = 0; p < 2; ++p) {
            int lin = p * 256 + tid;
            int c = lin >> 2;
            int qq = ((lin & 3) ^ c ^ (c >> 2)) & 3;
            gl_lds16(wt + c * 576 + t * 32 + qq * 8, &sm.st.B[bb][lin * 8]);
        }
    };

    stage(0, 0);
    for (int t = 0; t < 18; ++t) {
        const int bb = t & 1;
        __syncthreads();                    // drains vmcnt -> buf bb ready
        if (t + 1 < 18) stage(bb ^ 1, t + 1);
        s16x8_t af[4], bfr[4];
        #pragma unroll
        for (int mi = 0; mi < 4; ++mi) {
            int r = wr * 64 + mi * 16 + m;
            s16x4_t lo = *(const s16x4_t*)&sm.st.A[bb][(2 * q) * 512 + r * 4];
            s16x4_t hi = *(const s16x4_t*)&sm.st.A[bb][(2 * q + 1) * 512 + r * 4];
            af[mi] = __builtin_shufflevector(lo, hi, 0, 1, 2, 3, 4, 5, 6, 7);
        }
        #pragma unroll
        for (int ni = 0; ni < 4; ++ni) {
            int c = (ni < 2) ? (wc * 32 + ni * 16 + m) : (64 + wc * 32 + (ni - 2) * 16 + m);
            int slot = (q ^ c ^ (c >> 2)) & 3;
            bfr[ni] = *(const s16x8_t*)&sm.st.B[bb][(c * 4 + slot) * 8];
        }
        #pragma unroll
        for (int mi = 0; mi < 4; ++mi)
            #pragma unroll
            for (int ni = 0; ni < 4; ++ni)
                acc[mi][ni] = __builtin_amdgcn_mfma_f32_16x16x32_bf16(af[mi], bfr[ni], acc[mi][ni], 0, 0, 0);
    }
    __syncthreads();   // all ds_reads done before heh overwrites staging

    #pragma unroll
    for (int mi = 0; mi < 4; ++mi) {
        #pragma unroll
        for (int ni = 0; ni < 2; ++ni) {
            const int f = wc * 32 + ni * 16 + m;
            const float vbz = sBz[f], vbh = sBh[f];
            #pragma unroll
            for (int r = 0; r < 4; ++r) {
                const int rl = wr * 64 + mi * 16 + q * 4 + r;
                float zp = acc[mi][ni][r];
                float hp = acc[mi][ni + 2][r];
                zp = (zp == zp) ? zp : 0.f;
                hp = (hp == hp) ? hp : 0.f;
                zp = fminf(fmaxf(zp + vbz, -30.f), 30.f);
                hp = fminf(fmaxf(hp + vbh, -15.f), 15.f);
                const float z = __fdividef(1.f, 1.f + __expf(-zp));
                const float e2 = __expf(2.f * hp);
                const float ht = __fdividef(e2 - 1.f, e2 + 1.f);
                float h = (1.f - z) * ht;
                h = fmaxf(h, 0.f);
                sm.heh[rl * 65 + f] = h;
            }
        }
    }
    __syncthreads();
    if (tid < 128) {
        float sum = 0.f, ss = 0.f;
        #pragma unroll 8
        for (int f = 0; f < 64; ++f) {
            float v = sm.heh[tid * 65 + f];
            sum += v; ss += v * v;
        }
        float mu = sum * 0.015625f;
        float var = fmaxf(ss * 0.015625f - mu * mu, 0.f);
        sMu[tid] = mu;
        sRs[tid] = rsqrtf(var + 1e-5f);
    }
    __syncthreads();
    for (int idx = tid; idx < 128 * 64; idx += 256) {
        int rl = idx >> 6, f = idx & 63;
        if (r0 + rl < rchv) {
            float v = (sm.heh[rl * 65 + f] - sMu[rl]) * sRs[rl] * sG[f] + sB2[f];
            hnc[(size_t)(r0 + rl) * 64 + f] = f2bf(v);
        }
    }
}

// ---------------- phase 3: final linear, atomic accumulate into obuf[160] ----------------

__global__ __launch_bounds__(256) void k_lin_chunk(const u16* __restrict__ hnc,
        const void* __restrict__ lw, float* __restrict__ obuf, int s0, int chs,
        const int* __restrict__ flags) {
    const int tid = threadIdx.x;
    const int f32m = flags[0];
    float acc[NB][NC];
    #pragma unroll
    for (int b = 0; b < NB; ++b)
        #pragma unroll
        for (int c = 0; c < NC; ++c) acc[b][c] = 0.f;

    const int hi_s = s0 + chs - 1;
    for (int w = blockIdx.x * 256 + tid; w < TNF; w += LWG2 * 256) {
        const int t = w / 64000;
        int blo_n = s0 - t + 11;
        const int blo = (blo_n > 0) ? (blo_n / 12) : 0;
        const int bhi_n = hi_s - t;
        const int bhi = (bhi_n >= 0) ? (bhi_n / 12) : -1;
        if (bhi < blo) continue;
        float wvv[NC];
        if (f32m) {
            #pragma unroll
            for (int c = 0; c < NC; ++c) wvv[c] = ((const float*)lw)[(size_t)c * TNF + w];
        } else {
            #pragma unroll
            for (int c = 0; c < NC; ++c) wvv[c] = bf2f(((const u16*)lw)[(size_t)c * TNF + w]);
        }
        #pragma unroll
        for (int c = 0; c < NC; ++c) {
            float v = wvv[c];
            wvv[c] = (v == v && v > -1e30f && v < 1e30f) ? v : 0.f;
        }
        #pragma unroll
        for (int b = 0; b < NB; ++b) {
            if (b >= blo && b <= bhi) {
                const int sl = b * 12 + t - s0;
                const float h = bf2f(hnc[(size_t)sl * 64000 + (w - t * 64000)]);
                #pragma unroll
                for (int c = 0; c < NC; ++c) acc[b][c] = fmaf(h, wvv[c], acc[b][c]);
            }
        }
    }
    __shared__ float sRed[4][160];
    const int wvi = tid >> 6, lane = tid & 63;
    #pragma unroll
    for (int b = 0; b < NB; ++b)
        #pragma unroll
        for (int c = 0; c < NC; ++c) {
            float v = acc[b][c];
            #pragma unroll
            for (int off = 1; off < 64; off <<= 1) v += __shfl_xor(v, off, 64);
            if (lane == 0) sRed[wvi][b * NC + c] = v;
        }
    __syncthreads();
    if (tid < 160)
        atomicAdd(&obuf[tid], sRed[0][tid] + sRed[1][tid] + sRed[2][tid] + sRed[3][tid]);
}

__global__ void k_red(const float* __restrict__ obuf, const void* __restrict__ lb,
                      void* __restrict__ out, const int* __restrict__ flags) {
    const int o = threadIdx.x;
    const int f32m = flags[0];
    if (o < 160) {
        float s = obuf[o] + ldf(lb, o % NC, f32m);
        if (f32m) ((float*)out)[o] = s;
        else      ((u16*)out)[o] = f2bf(s);
    }
}

// ---------------- launch ----------------

extern "C" void kernel_launch(void* const* d_in, const int* in_sizes, int n_in,
                              void* d_out, int out_size, void* d_ws, size_t ws_size,
                              hipStream_t stream) {
    (void)in_sizes; (void)n_in; (void)out_size;
    const void* x   = d_in[0];
    const int*  ei  = (const int*)d_in[1];
    const void* Wz  = d_in[2];
    const void* bz  = d_in[3];
    const void* Wh  = d_in[6];
    const void* bh  = d_in[7];
    const void* lng = d_in[8];
    const void* lnb = d_in[9];
    const void* lw  = d_in[10];
    const void* lb  = d_in[11];

    char* ws = (char*)d_ws;
    size_t off = 0;
    auto alloc = [&](size_t bytes) -> void* {
        void* p = ws + off;
        off = (off + bytes + 255) & ~(size_t)255;
        return p;
    };
    int*   flags    = (int*)  alloc(64);
    u16*   wt       = (u16*)  alloc(128 * 576 * 2);
    int*   ints     = (int*)  alloc(4000 * 4);
    int*   ooffp    = (int*)  alloc(1024 * 4);
    int*   ioffp    = (int*)  alloc(1024 * 4);
    float* inv_o    = (float*)alloc(1000 * 4);
    float* inv_i    = (float*)alloc(1000 * 4);
    u16*   eo_s     = (u16*)  alloc((size_t)EPAD * 2);
    u16*   eid_s    = (u16*)  alloc((size_t)EPAD * 2);
    float* obuf     = (float*)alloc(160 * 4);

    const int cand[] = {192, 96, 64, 48, 32, 24, 16, 12, 8, 6, 4, 3, 2, 1};
    int CHS = 1, RCHP = 1024;
    for (int ci = 0; ci < 14; ++ci) {
        int c = cand[ci];
        int rchp = ((c * NN + 127) / 128) * 128;
        size_t need = (size_t)16 * 9 * rchp * 8 + (size_t)c * NN * FF * 2 + 8192;
        if (off + need <= ws_size) { CHS = c; RCHP = rchp; break; }
    }
    u16* basis = (u16*)alloc((size_t)16 * 9 * RCHP * 8);
    u16* hnc   = (u16*)alloc((size_t)CHS * NN * FF * 2);

    int* deg_out = ints;
    int* deg_in  = ints + 1000;
    int* cur     = ints + 2000;

    k_pre<<<160, 256, 0, stream>>>((const u16*)x, ei, flags, ints, obuf, eo_s, eid_s);
    k_deg<<<(EE + 255) / 256, 256, 0, stream>>>(ei, ints, flags);
    k_scan<<<1, 1024, 0, stream>>>(deg_in, deg_out, ooffp, ioffp, inv_o, inv_i);
    k_fill<<<(EE + 255) / 256, 256, 0, stream>>>(ei, ooffp, ioffp, cur, eo_s, eid_s, flags);
    k_wt<<<288, 256, 0, stream>>>(Wz, Wh, wt, flags);
    const int nchunk = SS / CHS;
    for (int ch = 0; ch < nchunk; ++ch) {
        k_cheb<<<CHS * 16, 1024, 0, stream>>>(x, eo_s, ooffp, eid_s, ioffp, inv_o, inv_i,
                                              basis, ch * CHS, RCHP, flags, CHS);
        k_gemm<<<RCHP / 128, 256, 0, stream>>>(basis, wt, bz, bh, lng, lnb, hnc,
                                               RCHP, CHS * NN, flags);
        k_lin_chunk<<<LWG2, 256, 0, stream>>>(hnc, lw, obuf, ch * CHS, CHS, flags);
    }
    k_red<<<1, 256, 0, stream>>>(obuf, lb, d_out, flags);
}

// Round 9
// 483.045 us; speedup vs baseline: 1.9571x; 1.1120x over previous
//
#include <hip/hip_runtime.h>

#define NN   1000
#define EE   16000
#define FF   64
#define SS   192
#define TNF  768000
#define NB   16
#define NC   10
#define LWG2 1024  // k_lin_chunk grid (4 blocks/CU)
#define EPAD 24576 // padded edge-list capacity (sum ceil(deg/8)*8 <= 23000)

typedef unsigned short u16;
typedef unsigned int   u32;
typedef float f32x4_t __attribute__((ext_vector_type(4)));
typedef short s16x4_t __attribute__((ext_vector_type(4)));
typedef short s16x8_t __attribute__((ext_vector_type(8)));
typedef _Float16 f16x2_t __attribute__((ext_vector_type(2)));
typedef _Float16 f16x8_t __attribute__((ext_vector_type(8)));

__device__ __forceinline__ float bf2f(u16 u) {
    return __uint_as_float(((u32)u) << 16);
}
__device__ __forceinline__ u16 f2bf(float f) {
    u32 u = __float_as_uint(f);
    u32 r = u + 0x7FFFu + ((u >> 16) & 1u);
    return (u16)(r >> 16);
}
__device__ __forceinline__ u16 f2h(float f) {
    _Float16 h = (_Float16)f;   // v_cvt_f16_f32 (RNE)
    return __builtin_bit_cast(unsigned short, h);
}
// flag-dispatched scalar float load (f32m: 1 = fp32 array, 0 = bf16 array)
__device__ __forceinline__ float ldf(const void* p, size_t i, int f32m) {
    return f32m ? ((const float*)p)[i] : bf2f(((const u16*)p)[i]);
}

// pack float4 -> 4 f16 in a uint2
__device__ __forceinline__ uint2 pk4h(float4 v) {
    uint2 p;
    p.x = (u32)f2h(v.x) | ((u32)f2h(v.y) << 16);
    p.y = (u32)f2h(v.z) | ((u32)f2h(v.w) << 16);
    return p;
}

// async global->LDS 16B copy (dest must be wave-uniform base + lane*16)
__device__ __forceinline__ void gl_lds16(const void* src, void* dst) {
    __builtin_amdgcn_global_load_lds(
        (const __attribute__((address_space(1))) unsigned int*)src,
        (__attribute__((address_space(3))) unsigned int*)dst, 16, 0, 0);
}

// ---------------- merged prep: detect + zero + edge-list prefill ----------------
// edge lists hold BYTE offsets (idx*8); dummy = 1000*8 = 8000 = 0x1F40
__global__ void k_pre(const u16* __restrict__ x, const int* __restrict__ ei,
                      int* __restrict__ flags, int* __restrict__ ints,
                      float* __restrict__ obuf, u16* __restrict__ eo_s,
                      u16* __restrict__ eid_s) {
    const int i = blockIdx.x * 256 + threadIdx.x;
    if (blockIdx.x == 0 && threadIdx.x < 64) {   // wave 0: parallel dtype detect
        const int lane = threadIdx.x;
        u16 u1 = x[2 * lane], u2 = x[2 * (lane + 64)];
        int e1 = (u1 >> 7) & 0xFF, e2 = (u2 >> 7) & 0xFF;
        int ok1 = (u1 == 0 || (e1 >= 100 && e1 <= 140)) ? 1 : 0;
        int ok2 = (u2 == 0 || (e2 >= 100 && e2 <= 140)) ? 1 : 0;
        unsigned long long b1 = __ballot(ok1), b2 = __ballot(ok2);
        int nzf = (lane < 32 && ei[2 * lane + 1] != 0) ? 1 : 0;
        unsigned long long b3 = __ballot(nzf);
        if (lane == 0) {
            int good = __popcll(b1) + __popcll(b2);
            flags[0] = (good < 96) ? 1 : 0;           // <75% plausible -> fp32
            flags[1] = (__popcll(b3) <= 4) ? 1 : 0;   // odd words all zero -> int64
        }
    }
    if (i < 4000) ints[i] = 0;
    if (i < 160) obuf[i] = 0.f;
    if (i < EPAD / 2) {
        ((u32*)eo_s)[i] = 0x1F401F40u;
        ((u32*)eid_s)[i] = 0x1F401F40u;
    }
}

__global__ void k_deg(const int* __restrict__ ei, int* __restrict__ deg,
                      const int* __restrict__ flags) {
    int e = blockIdx.x * 256 + threadIdx.x;
    const int sh = flags[1];
    if (e < EE) {
        int r = ei[(size_t)e << sh];
        int c = ei[(size_t)(EE + e) << sh];
        atomicAdd(&deg[r & 1023], 1);
        atomicAdd(&deg[NN + (c & 1023)], 1);
    }
}

// 8-padded CSR offsets + inverse degrees
__global__ __launch_bounds__(1024) void k_scan(const int* __restrict__ deg_in,
        const int* __restrict__ deg_out, int* __restrict__ ooffp, int* __restrict__ ioffp,
        float* __restrict__ inv_o, float* __restrict__ inv_i) {
    __shared__ int sa[1024], sb2[1024];
    const int t = threadIdx.x;
    for (int pass = 0; pass < 2; ++pass) {
        const int* deg = pass ? deg_out : deg_in;
        int* dst_off = pass ? ioffp : ooffp;
        sa[t] = (t < NN) ? ((deg[t] + 7) & ~7) : 0;
        __syncthreads();
        int* src = sa; int* dst = sb2;
        for (int offn = 1; offn < 1024; offn <<= 1) {
            int v = src[t];
            if (t >= offn) v += src[t - offn];
            dst[t] = v;
            __syncthreads();
            int* tmp = src; src = dst; dst = tmp;
        }
        if (t == 0) dst_off[0] = 0;
        if (t < NN) dst_off[t + 1] = src[t];
        __syncthreads();
    }
    if (t < NN) {
        inv_o[t] = 1.0f / (float)max(deg_out[t], 1);
        inv_i[t] = 1.0f / (float)max(deg_in[t], 1);
    }
}

__global__ void k_fill(const int* __restrict__ ei, const int* __restrict__ ooffp,
        const int* __restrict__ ioffp, int* __restrict__ cur,
        u16* __restrict__ eo_s, u16* __restrict__ eid_s,
        const int* __restrict__ flags) {
    int e = blockIdx.x * 256 + threadIdx.x;
    const int sh = flags[1];
    if (e < EE) {
        int r = ei[(size_t)e << sh] & 1023;
        int c = ei[(size_t)(EE + e) << sh] & 1023;
        int po = ooffp[c] + atomicAdd(&cur[c], 1);       // group by dst
        eo_s[po] = (u16)(r * 8);                          // byte offset
        int pi = ioffp[r] + atomicAdd(&cur[NN + r], 1);  // group by src
        eid_s[pi] = (u16)(c * 8);
    }
}

// Wt[col][kappa] (f16), kappa = j*64 + fi.  col<64 -> z (W_z), col>=64 -> h (W_h).
__global__ void k_wt(const void* __restrict__ Wz, const void* __restrict__ Wh,
                     u16* __restrict__ wt, const int* __restrict__ flags) {
    int idx = blockIdx.x * 256 + threadIdx.x;
    if (idx >= 128 * 576) return;
    const int f32m = flags[0];
    const int col = idx / 576;
    const int kk = idx - col * 576;
    const int j = kk >> 6, fi = kk & 63;
    const void* W = (col < 64) ? Wz : Wh;
    const int fo = col & 63;
    float v;
    if (j == 0) {
        v = ldf(W, (size_t)(0 * 128 + fi) * 64 + fo, f32m)
          + ldf(W, (size_t)(5 * 128 + fi) * 64 + fo, f32m);
    } else {
        const int d = (j & 1) ? 0 : 1;
        const int kq = (j + 1) >> 1;
        v = ldf(W, (size_t)((d * 5 + kq) * 128 + fi) * 64 + fo, f32m);
    }
    wt[col * 576 + kk] = f2h(v);
}

// ---------------- phase 1: Chebyshev basis ----------------
// basis: [sb(16)][j(9)][row(rchp)][f4(4)] f16
// LDS state: packed f16x4 (uint2). Gather accumulates IN PACKED f16
// (v_pk_add_f16, 2 features/op — no unpack) across 2 interleaved chains;
// widened to f32 only at phase end. Edge lists store byte offsets (idx*8).
// Recurrence history (x, T1o, T2o) stays f32 in registers (quirk-exact).

__device__ __forceinline__ float4 g8h(const char* __restrict__ S,
                                      const u16* __restrict__ lst, int e0, int e1) {
    f16x2_t a0 = {(_Float16)0, (_Float16)0}, a1 = a0, b0 = a0, b1 = a0;
    for (int e = e0; e < e1; e += 8) {
        uint4 w = *(const uint4*)(lst + e);   // 8 u16 byte-offsets, 16B aligned
        int i0 = w.x & 0xFFFF, i1 = w.x >> 16;
        int i2 = w.y & 0xFFFF, i3 = w.y >> 16;
        int i4 = w.z & 0xFFFF, i5 = w.z >> 16;
        int i6 = w.w & 0xFFFF, i7 = w.w >> 16;
        uint2 q0 = *(const uint2*)(S + i0), q1 = *(const uint2*)(S + i1);
        uint2 q2 = *(const uint2*)(S + i2), q3 = *(const uint2*)(S + i3);
        uint2 q4 = *(const uint2*)(S + i4), q5 = *(const uint2*)(S + i5);
        uint2 q6 = *(const uint2*)(S + i6), q7 = *(const uint2*)(S + i7);
        a0 += __builtin_bit_cast(f16x2_t, q0.x); a1 += __builtin_bit_cast(f16x2_t, q0.y);
        b0 += __builtin_bit_cast(f16x2_t, q1.x); b1 += __builtin_bit_cast(f16x2_t, q1.y);
        a0 += __builtin_bit_cast(f16x2_t, q2.x); a1 += __builtin_bit_cast(f16x2_t, q2.y);
        b0 += __builtin_bit_cast(f16x2_t, q3.x); b1 += __builtin_bit_cast(f16x2_t, q3.y);
        a0 += __builtin_bit_cast(f16x2_t, q4.x); a1 += __builtin_bit_cast(f16x2_t, q4.y);
        b0 += __builtin_bit_cast(f16x2_t, q5.x); b1 += __builtin_bit_cast(f16x2_t, q5.y);
        a0 += __builtin_bit_cast(f16x2_t, q6.x); a1 += __builtin_bit_cast(f16x2_t, q6.y);
        b0 += __builtin_bit_cast(f16x2_t, q7.x); b1 += __builtin_bit_cast(f16x2_t, q7.y);
    }
    float4 r;
    r.x = (float)a0.x + (float)b0.x;
    r.y = (float)a0.y + (float)b0.y;
    r.z = (float)a1.x + (float)b1.x;
    r.w = (float)a1.y + (float)b1.y;
    return r;
}

__global__ __launch_bounds__(1024) void k_cheb(const void* __restrict__ xv_,
        const u16* __restrict__ eo_s, const int* __restrict__ ooffp,
        const u16* __restrict__ eid_s, const int* __restrict__ ioffp,
        const float* __restrict__ inv_o, const float* __restrict__ inv_i,
        u16* __restrict__ basis, int s0, int rchp,
        const int* __restrict__ flags, int chs) {
    __shared__ uint2 bXo[1024], bXi[1024], bA[1024], bB[1024];
    const int sb = blockIdx.x / chs;
    const int slocal = blockIdx.x - sb * chs;
    const int s = s0 + slocal;
    const int n = threadIdx.x;
    const bool act = (n < NN);
    const int f32m = flags[0];
    int e0o = 0, e1o = 0, e0i = 0, e1i = 0;
    float fiv = 0.f, fov = 0.f;
    const int row = slocal * NN + n;
    if (act) {
        e0o = ooffp[n]; e1o = ooffp[n + 1];
        e0i = ioffp[n]; e1i = ioffp[n + 1];
        fiv = inv_i[n];
        fov = inv_o[n];
    }
    const float fiv2 = 2.f * fiv;
    u16* const bp = basis + (size_t)(sb * 9) * rchp * 4 + (size_t)row * 4;
    const size_t jstep = (size_t)rchp * 4;   // u16s per j-plane
    float4 rx, rt1o, rt2o;
    if (n >= NN) {   // zero the dummy slots (1000..1023) in all buffers
        const uint2 z = make_uint2(0u, 0u);
        bXo[n] = z; bXi[n] = z; bA[n] = z; bB[n] = z;
    }
    if (act) {
        const size_t xoff = ((size_t)s * NN + n) * FF + sb * 4;
        if (f32m) {
            rx = *(const float4*)((const float*)xv_ + xoff);
        } else {
            ushort4 u = *(const ushort4*)((const u16*)xv_ + xoff);
            rx = make_float4(bf2f(u.x), bf2f(u.y), bf2f(u.z), bf2f(u.w));
        }
        bXi[n] = pk4h(rx);
        bXo[n] = pk4h(make_float4(fov * rx.x, fov * rx.y, fov * rx.z, fov * rx.w));
        *(uint2*)bp = pk4h(rx);                          // j0 raw
    }
    __syncthreads();
    // ph12: T1o = sum(bXo) ; T1i = fiv * sum(bXi)
    if (act) {
        float4 go = g8h((const char*)bXo, eo_s, e0o, e1o);
        float4 gi = g8h((const char*)bXi, eid_s, e0i, e1i);
        rt1o = go;
        bA[n] = pk4h(make_float4(fov * go.x, fov * go.y, fov * go.z, fov * go.w));
        *(uint2*)(bp + jstep) = pk4h(go);                // j1 raw
        float4 t = make_float4(gi.x * fiv, gi.y * fiv, gi.z * fiv, gi.w * fiv);
        bB[n] = pk4h(t);
        *(uint2*)(bp + 2 * jstep) = pk4h(t);             // j2 raw
    }
    __syncthreads();
    // ph34: T2o = 2*sum(bA) - x ; T2i = fiv2*sum(bB) - x
    if (act) {
        float4 go = g8h((const char*)bA, eo_s, e0o, e1o);
        float4 gi = g8h((const char*)bB, eid_s, e0i, e1i);
        float4 t2o = make_float4(fmaf(2.f, go.x, -rx.x), fmaf(2.f, go.y, -rx.y),
                                 fmaf(2.f, go.z, -rx.z), fmaf(2.f, go.w, -rx.w));
        rt2o = t2o;
        bXo[n] = pk4h(make_float4(fov * t2o.x, fov * t2o.y, fov * t2o.z, fov * t2o.w));
        *(uint2*)(bp + 3 * jstep) = pk4h(t2o);           // j3 raw
        float4 t2i = make_float4(fmaf(fiv2, gi.x, -rx.x), fmaf(fiv2, gi.y, -rx.y),
                                 fmaf(fiv2, gi.z, -rx.z), fmaf(fiv2, gi.w, -rx.w));
        bXi[n] = pk4h(t2i);
        *(uint2*)(bp + 4 * jstep) = pk4h(t2i);           // j4 raw
    }
    __syncthreads();
    // ph56: T3o = 2*sum(bXo) - T1o ; T3i = fiv2*sum(bXi) - T1o (quirk: both T1o)
    if (act) {
        float4 go = g8h((const char*)bXo, eo_s, e0o, e1o);
        float4 gi = g8h((const char*)bXi, eid_s, e0i, e1i);
        float4 t3o = make_float4(fmaf(2.f, go.x, -rt1o.x), fmaf(2.f, go.y, -rt1o.y),
                                 fmaf(2.f, go.z, -rt1o.z), fmaf(2.f, go.w, -rt1o.w));
        bA[n] = pk4h(make_float4(fov * t3o.x, fov * t3o.y, fov * t3o.z, fov * t3o.w));
        *(uint2*)(bp + 5 * jstep) = pk4h(t3o);           // j5 raw
        float4 t3i = make_float4(fmaf(fiv2, gi.x, -rt1o.x), fmaf(fiv2, gi.y, -rt1o.y),
                                 fmaf(fiv2, gi.z, -rt1o.z), fmaf(fiv2, gi.w, -rt1o.w));
        bB[n] = pk4h(t3i);
        *(uint2*)(bp + 6 * jstep) = pk4h(t3i);           // j6 raw
    }
    __syncthreads();
    // ph78: T4o = 2*sum(bA) - T2o ; T4i = fiv2*sum(bB) - T2o (quirk: both T2o)
    if (act) {
        float4 go = g8h((const char*)bA, eo_s, e0o, e1o);
        float4 gi = g8h((const char*)bB, eid_s, e0i, e1i);
        float4 t4o = make_float4(fmaf(2.f, go.x, -rt2o.x), fmaf(2.f, go.y, -rt2o.y),
                                 fmaf(2.f, go.z, -rt2o.z), fmaf(2.f, go.w, -rt2o.w));
        *(uint2*)(bp + 7 * jstep) = pk4h(t4o);           // j7
        float4 t4i = make_float4(fmaf(fiv2, gi.x, -rt2o.x), fmaf(fiv2, gi.y, -rt2o.y),
                                 fmaf(fiv2, gi.z, -rt2o.z), fmaf(fiv2, gi.w, -rt2o.w));
        *(uint2*)(bp + 8 * jstep) = pk4h(t4i);           // j8
    }
}

// ---------------- phase 2: GEMM (f16 MFMA) + gates + LN -> hnc ----------------

__global__ __launch_bounds__(256, 4) void k_gemm(const u16* __restrict__ basis,
        const u16* __restrict__ wt, const void* __restrict__ bz, const void* __restrict__ bh_,
        const void* __restrict__ lng, const void* __restrict__ lnb, u16* __restrict__ hnc,
        int rchp, int rchv, const int* __restrict__ flags) {
    union SM {
        struct { u16 A[2][4096]; u16 B[2][4096]; } st;   // 2 x (8KB+8KB)
        float heh[128 * 65];
    };
    __shared__ SM sm;
    __shared__ float sMu[128], sRs[128];
    __shared__ float sBz[64], sBh[64], sG[64], sB2[64];

    const int tid = threadIdx.x;
    if (tid < 64) {
        const int f32m = flags[0];
        sBz[tid] = ldf(bz, tid, f32m); sBh[tid] = ldf(bh_, tid, f32m);
        sG[tid] = ldf(lng, tid, f32m); sB2[tid] = ldf(lnb, tid, f32m);
    }
    const int lane = tid & 63, wv = tid >> 6;
    const int wr = wv >> 1, wc = wv & 1;
    const int m = lane & 15, q = lane >> 4;
    const int r0 = blockIdx.x * 128;

    f32x4_t acc[4][4];
    const f32x4_t zero = {0.f, 0.f, 0.f, 0.f};
    for (int mi = 0; mi < 4; ++mi)
        for (int ni = 0; ni < 4; ++ni) acc[mi][ni] = zero;

    auto stage = [&](int bb, int t) {
        const int j = t >> 1, hf = t & 1;
        #pragma unroll
        for (int p = 0; p < 2; ++p) {
            int lin = p * 256 + tid;
            int sbp = lin >> 6, rp = lin & 63;
            const u16* src = basis + ((size_t)((hf * 8 + sbp) * 9 + j) * rchp + r0 + rp * 2) * 4;
            gl_lds16(src, &sm.st.A[bb][lin * 8]);
        }
        #pragma unroll
        for (int p = 0; p < 2; ++p) {
            int lin = p * 256 + tid;
            int c = lin >> 2;
            int qq = ((lin & 3) ^ c ^ (c >> 2)) & 3;
            gl_lds16(wt + c * 576 + t * 32 + qq * 8, &sm.st.B[bb][lin * 8]);
        }
    };

    stage(0, 0);
    for (int t = 0; t < 18; ++t) {
        const int bb = t & 1;
        __syncthreads();                    // drains vmcnt -> buf bb ready
        if (t + 1 < 18) stage(bb ^ 1, t + 1);
        s16x8_t af[4], bfr[4];
        #pragma unroll
        for (int mi = 0; mi < 4; ++mi) {
            int r = wr * 64 + mi * 16 + m;
            s16x4_t lo = *(const s16x4_t*)&sm.st.A[bb][(2 * q) * 512 + r * 4];
            s16x4_t hi = *(const s16x4_t*)&sm.st.A[bb][(2 * q + 1) * 512 + r * 4];
            af[mi] = __builtin_shufflevector(lo, hi, 0, 1, 2, 3, 4, 5, 6, 7);
        }
        #pragma unroll
        for (int ni = 0; ni < 4; ++ni) {
            int c = (ni < 2) ? (wc * 32 + ni * 16 + m) : (64 + wc * 32 + (ni - 2) * 16 + m);
            int slot = (q ^ c ^ (c >> 2)) & 3;
            bfr[ni] = *(const s16x8_t*)&sm.st.B[bb][(c * 4 + slot) * 8];
        }
        #pragma unroll
        for (int mi = 0; mi < 4; ++mi)
            #pragma unroll
            for (int ni = 0; ni < 4; ++ni)
                acc[mi][ni] = __builtin_amdgcn_mfma_f32_16x16x32_f16(
                    __builtin_bit_cast(f16x8_t, af[mi]),
                    __builtin_bit_cast(f16x8_t, bfr[ni]), acc[mi][ni], 0, 0, 0);
    }
    __syncthreads();   // all ds_reads done before heh overwrites staging

    #pragma unroll
    for (int mi = 0; mi < 4; ++mi) {
        #pragma unroll
        for (int ni = 0; ni < 2; ++ni) {
            const int f = wc * 32 + ni * 16 + m;
            const float vbz = sBz[f], vbh = sBh[f];
            #pragma unroll
            for (int r = 0; r < 4; ++r) {
                const int rl = wr * 64 + mi * 16 + q * 4 + r;
                float zp = acc[mi][ni][r];
                float hp = acc[mi][ni + 2][r];
                zp = (zp == zp) ? zp : 0.f;
                hp = (hp == hp) ? hp : 0.f;
                zp = fminf(fmaxf(zp + vbz, -30.f), 30.f);
                hp = fminf(fmaxf(hp + vbh, -15.f), 15.f);
                const float z = __fdividef(1.f, 1.f + __expf(-zp));
                const float e2 = __expf(2.f * hp);
                const float ht = __fdividef(e2 - 1.f, e2 + 1.f);
                float h = (1.f - z) * ht;
                h = fmaxf(h, 0.f);
                sm.heh[rl * 65 + f] = h;
            }
        }
    }
    __syncthreads();
    if (tid < 128) {
        float sum = 0.f, ss = 0.f;
        #pragma unroll 8
        for (int f = 0; f < 64; ++f) {
            float v = sm.heh[tid * 65 + f];
            sum += v; ss += v * v;
        }
        float mu = sum * 0.015625f;
        float var = fmaxf(ss * 0.015625f - mu * mu, 0.f);
        sMu[tid] = mu;
        sRs[tid] = rsqrtf(var + 1e-5f);
    }
    __syncthreads();
    for (int idx = tid; idx < 128 * 64; idx += 256) {
        int rl = idx >> 6, f = idx & 63;
        if (r0 + rl < rchv) {
            float v = (sm.heh[rl * 65 + f] - sMu[rl]) * sRs[rl] * sG[f] + sB2[f];
            hnc[(size_t)(r0 + rl) * 64 + f] = f2bf(v);
        }
    }
}

// ---------------- phase 3: final linear, atomic accumulate into obuf[160] ----------------

__global__ __launch_bounds__(256) void k_lin_chunk(const u16* __restrict__ hnc,
        const void* __restrict__ lw, float* __restrict__ obuf, int s0, int chs,
        const int* __restrict__ flags) {
    const int tid = threadIdx.x;
    const int f32m = flags[0];
    float acc[NB][NC];
    #pragma unroll
    for (int b = 0; b < NB; ++b)
        #pragma unroll
        for (int c = 0; c < NC; ++c) acc[b][c] = 0.f;

    const int hi_s = s0 + chs - 1;
    for (int w = blockIdx.x * 256 + tid; w < TNF; w += LWG2 * 256) {
        const int t = w / 64000;
        int blo_n = s0 - t + 11;
        const int blo = (blo_n > 0) ? (blo_n / 12) : 0;
        const int bhi_n = hi_s - t;
        const int bhi = (bhi_n >= 0) ? (bhi_n / 12) : -1;
        if (bhi < blo) continue;
        float wvv[NC];
        if (f32m) {
            #pragma unroll
            for (int c = 0; c < NC; ++c) wvv[c] = ((const float*)lw)[(size_t)c * TNF + w];
        } else {
            #pragma unroll
            for (int c = 0; c < NC; ++c) wvv[c] = bf2f(((const u16*)lw)[(size_t)c * TNF + w]);
        }
        #pragma unroll
        for (int c = 0; c < NC; ++c) {
            float v = wvv[c];
            wvv[c] = (v == v && v > -1e30f && v < 1e30f) ? v : 0.f;
        }
        #pragma unroll
        for (int b = 0; b < NB; ++b) {
            if (b >= blo && b <= bhi) {
                const int sl = b * 12 + t - s0;
                const float h = bf2f(hnc[(size_t)sl * 64000 + (w - t * 64000)]);
                #pragma unroll
                for (int c = 0; c < NC; ++c) acc[b][c] = fmaf(h, wvv[c], acc[b][c]);
            }
        }
    }
    __shared__ float sRed[4][160];
    const int wvi = tid >> 6, lane = tid & 63;
    #pragma unroll
    for (int b = 0; b < NB; ++b)
        #pragma unroll
        for (int c = 0; c < NC; ++c) {
            float v = acc[b][c];
            #pragma unroll
            for (int off = 1; off < 64; off <<= 1) v += __shfl_xor(v, off, 64);
            if (lane == 0) sRed[wvi][b * NC + c] = v;
        }
    __syncthreads();
    if (tid < 160)
        atomicAdd(&obuf[tid], sRed[0][tid] + sRed[1][tid] + sRed[2][tid] + sRed[3][tid]);
}

__global__ void k_red(const float* __restrict__ obuf, const void* __restrict__ lb,
                      void* __restrict__ out, const int* __restrict__ flags) {
    const int o = threadIdx.x;
    const int f32m = flags[0];
    if (o < 160) {
        float s = obuf[o] + ldf(lb, o % NC, f32m);
        if (f32m) ((float*)out)[o] = s;
        else      ((u16*)out)[o] = f2bf(s);
    }
}

// ---------------- launch ----------------

extern "C" void kernel_launch(void* const* d_in, const int* in_sizes, int n_in,
                              void* d_out, int out_size, void* d_ws, size_t ws_size,
                              hipStream_t stream) {
    (void)in_sizes; (void)n_in; (void)out_size;
    const void* x   = d_in[0];
    const int*  ei  = (const int*)d_in[1];
    const void* Wz  = d_in[2];
    const void* bz  = d_in[3];
    const void* Wh  = d_in[6];
    const void* bh  = d_in[7];
    const void* lng = d_in[8];
    const void* lnb = d_in[9];
    const void* lw  = d_in[10];
    const void* lb  = d_in[11];

    char* ws = (char*)d_ws;
    size_t off = 0;
    auto alloc = [&](size_t bytes) -> void* {
        void* p = ws + off;
        off = (off + bytes + 255) & ~(size_t)255;
        return p;
    };
    int*   flags    = (int*)  alloc(64);
    u16*   wt       = (u16*)  alloc(128 * 576 * 2);
    int*   ints     = (int*)  alloc(4000 * 4);
    int*   ooffp    = (int*)  alloc(1024 * 4);
    int*   ioffp    = (int*)  alloc(1024 * 4);
    float* inv_o    = (float*)alloc(1000 * 4);
    float* inv_i    = (float*)alloc(1000 * 4);
    u16*   eo_s     = (u16*)  alloc((size_t)EPAD * 2);
    u16*   eid_s    = (u16*)  alloc((size_t)EPAD * 2);
    float* obuf     = (float*)alloc(160 * 4);

    const int cand[] = {192, 96, 64, 48, 32, 24, 16, 12, 8, 6, 4, 3, 2, 1};
    int CHS = 1, RCHP = 1024;
    for (int ci = 0; ci < 14; ++ci) {
        int c = cand[ci];
        int rchp = ((c * NN + 127) / 128) * 128;
        size_t need = (size_t)16 * 9 * rchp * 8 + (size_t)c * NN * FF * 2 + 8192;
        if (off + need <= ws_size) { CHS = c; RCHP = rchp; break; }
    }
    u16* basis = (u16*)alloc((size_t)16 * 9 * RCHP * 8);
    u16* hnc   = (u16*)alloc((size_t)CHS * NN * FF * 2);

    int* deg_out = ints;
    int* deg_in  = ints + 1000;
    int* cur     = ints + 2000;

    k_pre<<<160, 256, 0, stream>>>((const u16*)x, ei, flags, ints, obuf, eo_s, eid_s);
    k_deg<<<(EE + 255) / 256, 256, 0, stream>>>(ei, ints, flags);
    k_scan<<<1, 1024, 0, stream>>>(deg_in, deg_out, ooffp, ioffp, inv_o, inv_i);
    k_fill<<<(EE + 255) / 256, 256, 0, stream>>>(ei, ooffp, ioffp, cur, eo_s, eid_s, flags);
    k_wt<<<288, 256, 0, stream>>>(Wz, Wh, wt, flags);
    const int nchunk = SS / CHS;
    for (int ch = 0; ch < nchunk; ++ch) {
        k_cheb<<<CHS * 16, 1024, 0, stream>>>(x, eo_s, ooffp, eid_s, ioffp, inv_o, inv_i,
                                              basis, ch * CHS, RCHP, flags, CHS);
        k_gemm<<<RCHP / 128, 256, 0, stream>>>(basis, wt, bz, bh, lng, lnb, hnc,
                                               RCHP, CHS * NN, flags);
        k_lin_chunk<<<LWG2, 256, 0, stream>>>(hnc, lw, obuf, ch * CHS, CHS, flags);
    }
    k_red<<<1, 256, 0, stream>>>(obuf, lb, d_out, flags);
}